// Round 6
// baseline (240.148 us; speedup 1.0000x reference)
//
#include <hip/hip_runtime.h>

#define IN_DIM 128
#define HEADS 4
#define OUT_DIM 32
#define NEG 0.2f

#define NPB 256        // nodes per bucket (power of 2; bucket = dst >> 8)
#define NB_MAX 400     // max buckets (N=100000 -> 391)
#define EPB 2048       // edges per block in hist/bin kernels (782 blocks -> ~3/CU)

typedef unsigned int uint;
typedef unsigned short ushort_t;
typedef short short8 __attribute__((ext_vector_type(8)));
typedef float f32x4 __attribute__((ext_vector_type(4)));
typedef uint u32x4 __attribute__((ext_vector_type(4)));

__device__ __forceinline__ uint bf16r(float f) {
    uint u = __float_as_uint(f);
    return (u + 0x7fffu + ((u >> 16) & 1u)) >> 16;   // RNE
}

// ---------------- W^T bf16 prep: wt[n][k] = bf16(W[k][n]) -----------------
__global__ __launch_bounds__(256) void wt_prep_kernel(
    const float* __restrict__ fc_w, ushort_t* __restrict__ wt)
{
    int t = blockIdx.x * 256 + threadIdx.x;   // 64 blocks x 256 = 16384
    int n = t >> 7, k = t & 127;
    wt[t] = (ushort_t)bf16r(fc_w[k * 128 + n]);
}

// ---------------- projection via MFMA (no LDS) ----------------------------
__global__ __launch_bounds__(256) void proj_kernel(
    const float* __restrict__ x, const ushort_t* __restrict__ wt,
    const float* __restrict__ attn_l, const float* __restrict__ attn_r,
    ushort_t* __restrict__ feat16, float* __restrict__ el, float* __restrict__ er,
    int N)
{
    const int lane = threadIdx.x & 63;
    const int w    = threadIdx.x >> 6;
    const int rowbase = blockIdx.x * 64 + w * 16;
    const int c = lane & 15;
    const int g = lane >> 4;

    f32x4 acc[8];
    #pragma unroll
    for (int nt = 0; nt < 8; ++nt) acc[nt] = (f32x4){0.f, 0.f, 0.f, 0.f};

    const int arow  = rowbase + c;
    const int arowc = (arow < N) ? arow : (N - 1);     // clamp OOB reads
    const float* xrow = x + (size_t)arowc * 128 + g * 8;

    #pragma unroll
    for (int kk = 0; kk < 4; ++kk) {
        const float* xp = xrow + kk * 32;
        float4 f0 = *(const float4*)xp;
        float4 f1 = *(const float4*)(xp + 4);
        u32x4 au;
        au.x = bf16r(f0.x) | (bf16r(f0.y) << 16);
        au.y = bf16r(f0.z) | (bf16r(f0.w) << 16);
        au.z = bf16r(f1.x) | (bf16r(f1.y) << 16);
        au.w = bf16r(f1.z) | (bf16r(f1.w) << 16);
        short8 afrag = __builtin_bit_cast(short8, au);
        #pragma unroll
        for (int nt = 0; nt < 8; ++nt) {
            const ushort_t* wp = wt + ((nt * 16 + c) * 128 + kk * 32 + g * 8);
            u32x4 bu = *(const u32x4*)wp;               // 16B aligned
            short8 bfrag = __builtin_bit_cast(short8, bu);
            acc[nt] = __builtin_amdgcn_mfma_f32_16x16x32_bf16(afrag, bfrag, acc[nt], 0, 0, 0);
        }
    }

    float alv[4][2], arv[4][2];
    #pragma unroll
    for (int h = 0; h < 4; ++h) {
        alv[h][0] = attn_l[h * 32 + c];
        alv[h][1] = attn_l[h * 32 + 16 + c];
        arv[h][0] = attn_r[h * 32 + c];
        arv[h][1] = attn_r[h * 32 + 16 + c];
    }

    #pragma unroll
    for (int r = 0; r < 4; ++r) {
        const int node = rowbase + g * 4 + r;
        const bool ok = (node < N);
        ushort_t* fp = feat16 + (size_t)node * 128 + c;
        #pragma unroll
        for (int nt = 0; nt < 8; ++nt) {
            if (ok) fp[nt * 16] = (ushort_t)bf16r(acc[nt][r]);
        }
        #pragma unroll
        for (int h = 0; h < 4; ++h) {
            float accl = acc[2*h][r] * alv[h][0] + acc[2*h+1][r] * alv[h][1];
            float accr = acc[2*h][r] * arv[h][0] + acc[2*h+1][r] * arv[h][1];
            accl += __shfl_xor(accl, 1); accl += __shfl_xor(accl, 2);
            accl += __shfl_xor(accl, 4); accl += __shfl_xor(accl, 8);
            accr += __shfl_xor(accr, 1); accr += __shfl_xor(accr, 2);
            accr += __shfl_xor(accr, 4); accr += __shfl_xor(accr, 8);
            if (ok && c == 0) {
                el[node * 4 + h] = accl;
                er[node * 4 + h] = accr;
            }
        }
    }
}

// ---------------- CSR build: 2-level multisplit ---------------------------
__global__ __launch_bounds__(256) void coarse_hist_kernel(
    const int* __restrict__ edst, int* __restrict__ bucketCount, int E, int NB)
{
    __shared__ int h[NB_MAX];
    for (int t = threadIdx.x; t < NB_MAX; t += 256) h[t] = 0;
    __syncthreads();
    const int base = blockIdx.x * EPB;
    #pragma unroll
    for (int rep = 0; rep < EPB / 1024; ++rep) {
        int i = base + (rep * 256 + threadIdx.x) * 4;
        if (i + 3 < E) {
            int4 d = *(const int4*)(edst + i);
            atomicAdd(&h[d.x >> 8], 1);
            atomicAdd(&h[d.y >> 8], 1);
            atomicAdd(&h[d.z >> 8], 1);
            atomicAdd(&h[d.w >> 8], 1);
        } else {
            for (int k = 0; k < 4; ++k)
                if (i + k < E) atomicAdd(&h[edst[i + k] >> 8], 1);
        }
    }
    __syncthreads();
    for (int t = threadIdx.x; t < NB; t += 256)
        if (h[t]) atomicAdd(&bucketCount[t], h[t]);
}

__global__ __launch_bounds__(512) void bucket_scan_kernel(
    const int* __restrict__ bucketCount, int* __restrict__ bucketStart,
    int* __restrict__ bucketCursor, int* __restrict__ row_start, int NB, int N)
{
    __shared__ int p[512];
    const int t = threadIdx.x;
    int v = (t < NB) ? bucketCount[t] : 0;
    p[t] = v;
    __syncthreads();
    for (int off = 1; off < 512; off <<= 1) {
        int u = (t >= off) ? p[t - off] : 0;
        __syncthreads();
        p[t] += u;
        __syncthreads();
    }
    if (t < NB) {
        bucketStart[t]  = p[t] - v;
        bucketCursor[t] = p[t] - v;
    }
    if (t == NB - 1) {
        bucketStart[NB] = p[t];
        row_start[N]    = p[t];   // == E
    }
}

__global__ __launch_bounds__(256) void bin_kernel(
    const int* __restrict__ esrc, const int* __restrict__ edst,
    int* __restrict__ bucketCursor, uint* __restrict__ binned, int E, int NB)
{
    __shared__ int dstS[EPB];      // 8 KB
    __shared__ int hist[NB_MAX];
    __shared__ int cur[NB_MAX];
    const int t = threadIdx.x;
    for (int k = t; k < NB_MAX; k += 256) hist[k] = 0;
    __syncthreads();

    const int base = blockIdx.x * EPB;
    #pragma unroll
    for (int rep = 0; rep < EPB / 1024; ++rep) {
        int idx4 = (rep * 256 + t) * 4;
        int i = base + idx4;
        if (i + 3 < E) {
            int4 d = *(const int4*)(edst + i);
            dstS[idx4]     = d.x; atomicAdd(&hist[d.x >> 8], 1);
            dstS[idx4 + 1] = d.y; atomicAdd(&hist[d.y >> 8], 1);
            dstS[idx4 + 2] = d.z; atomicAdd(&hist[d.z >> 8], 1);
            dstS[idx4 + 3] = d.w; atomicAdd(&hist[d.w >> 8], 1);
        } else {
            for (int k = 0; k < 4; ++k)
                if (i + k < E) {
                    int dv = edst[i + k];
                    dstS[idx4 + k] = dv;
                    atomicAdd(&hist[dv >> 8], 1);
                }
        }
    }
    __syncthreads();
    for (int k = t; k < NB; k += 256) {
        int hh = hist[k];
        cur[k] = hh ? atomicAdd(&bucketCursor[k], hh) : 0;
    }
    __syncthreads();
    const int nloc = min(EPB, E - base);
    for (int rep = 0; rep < EPB / 256; ++rep) {
        int idx = rep * 256 + t;
        if (idx < nloc) {
            int dv = dstS[idx];
            int pos = atomicAdd(&cur[dv >> 8], 1);
            int src = esrc[base + idx];                  // coalesced re-read
            binned[pos] = (uint)src | ((uint)(dv & 255) << 24);
        }
    }
}

__global__ __launch_bounds__(256) void fine_csr_kernel(
    const uint* __restrict__ binned, const int* __restrict__ bucketStart,
    int* __restrict__ row_start, int* __restrict__ csr, int N)
{
    __shared__ int hist[256], sc[256], cur[256];
    const int b = blockIdx.x;
    const int t = threadIdx.x;
    const int s = bucketStart[b];
    const int e = bucketStart[b + 1];

    hist[t] = 0;
    __syncthreads();
    for (int i = s + t; i < e; i += 256)
        atomicAdd(&hist[binned[i] >> 24], 1);
    __syncthreads();
    sc[t] = hist[t];
    __syncthreads();
    for (int off = 1; off < 256; off <<= 1) {
        int u = (t >= off) ? sc[t - off] : 0;
        __syncthreads();
        sc[t] += u;
        __syncthreads();
    }
    const int excl = s + sc[t] - hist[t];
    const int gn = b * NPB + t;
    if (gn < N) row_start[gn] = excl;
    cur[t] = excl;
    __syncthreads();
    for (int i = s + t; i < e; i += 256) {
        uint v = binned[i];
        int pos = atomicAdd(&cur[v >> 24], 1);
        csr[pos] = (int)(v & 0xFFFFFFu);
    }
}

// ---------------- aggregation: one wave per destination node --------------
// 16-edge chunks. Phase 1: lane=(head=l>>4, eix=l&15) computes exp for
// 16 edges x 4 heads with NO redundancy (was: 16 lanes per head computing
// identical e-math). Phase 2: per edge, u broadcast via readlane (const),
// x via one ds_bpermute; 16 feat gathers batched -> deep vmcnt queue.
__global__ __launch_bounds__(256) void aggregate_kernel(
    const uint* __restrict__ feat_b, const float* __restrict__ el,
    const float* __restrict__ er, const int* __restrict__ row_start,
    const int* __restrict__ csr, const float* __restrict__ bias,
    float* __restrict__ out, int N)
{
    int node = blockIdx.x * 4 + (threadIdx.x >> 6);
    node = __builtin_amdgcn_readfirstlane(node);
    if (node >= N) return;
    const int lane = threadIdx.x & 63;
    const int h   = lane >> 4;    // head group for phase-1 AND feature lane
    const int eix = lane & 15;

    const float er_vh = er[node * 4 + h];
    const int start = row_start[node];
    const int end   = row_start[node + 1];

    float r0 = 0.f, r1 = 0.f, s = 0.f;

    for (int i0 = start; i0 < end; i0 += 16) {
        const int rem = end - i0;                 // wave-uniform
        // ---- phase 1: exp weights, lane-parallel over (edge, head) ----
        int u = csr[i0 + ((eix < rem) ? eix : (rem - 1))];
        float e = el[u * 4 + h] + er_vh;
        e = fmaxf(e, NEG * e);
        float xw = __expf(e);
        xw = (eix < rem) ? xw : 0.f;
        s += xw;

        // ---- phase 2: batched feat gathers + broadcast-weighted fma ----
        const int nk = (rem < 16) ? rem : 16;     // wave-uniform
        uint pbuf[16];
        #pragma unroll
        for (int e2 = 0; e2 < 16; ++e2) {
            if (e2 >= nk) break;
            int ue = __builtin_amdgcn_readlane(u, e2);   // lane e2 holds edge e2
            pbuf[e2] = feat_b[(size_t)ue * 64 + lane];
        }
        #pragma unroll
        for (int e2 = 0; e2 < 16; ++e2) {
            if (e2 >= nk) break;
            float xe = __shfl(xw, (lane & 48) | e2);     // x(edge e2, my head)
            uint p = pbuf[e2];
            r0 = fmaf(xe, __uint_as_float(p << 16), r0);
            r1 = fmaf(xe, __uint_as_float(p & 0xffff0000u), r1);
        }
    }

    // softmax denominator: sum over the 16 lanes of each head group
    s += __shfl_xor(s, 1); s += __shfl_xor(s, 2);
    s += __shfl_xor(s, 4); s += __shfl_xor(s, 8);
    s = fmaxf(s, 1e-16f);
    r0 /= s;
    r1 /= s;
    // head mean: lanes {l, l^16, l^32, l^48} hold same d, different heads
    r0 += __shfl_xor(r0, 16); r0 += __shfl_xor(r0, 32);
    r1 += __shfl_xor(r1, 16); r1 += __shfl_xor(r1, 32);

    if (lane < 16) {
        int dd = lane * 2;
        float bm0 = 0.25f * (bias[dd]     + bias[32 + dd] + bias[64 + dd] + bias[96 + dd]);
        float bm1 = 0.25f * (bias[dd + 1] + bias[33 + dd] + bias[65 + dd] + bias[97 + dd]);
        float2 o;
        o.x = 0.25f * r0 + bm0;
        o.y = 0.25f * r1 + bm1;
        ((float2*)out)[(size_t)node * 16 + lane] = o;
    }
}

// ---------------- launch --------------------------------------------------
extern "C" void kernel_launch(void* const* d_in, const int* in_sizes, int n_in,
                              void* d_out, int out_size, void* d_ws, size_t ws_size,
                              hipStream_t stream)
{
    const float* x      = (const float*)d_in[0];
    const int*   esrc   = (const int*)  d_in[1];
    const int*   edst   = (const int*)  d_in[2];
    const float* fc_w   = (const float*)d_in[3];
    const float* attn_l = (const float*)d_in[4];
    const float* attn_r = (const float*)d_in[5];
    const float* bias   = (const float*)d_in[6];
    float* out = (float*)d_out;

    const int N = in_sizes[0] / IN_DIM;   // 100000
    const int E = in_sizes[1];            // 1600000
    const int NB = (N + NPB - 1) / NPB;   // 391

    size_t o = 0;
    char* base = (char*)d_ws;
    auto alloc = [&](size_t bytes) -> void* {
        void* p = base + o;
        o += (bytes + 255) & ~(size_t)255;
        return p;
    };
    ushort_t* feat16   = (ushort_t*)alloc((size_t)N * 128 * sizeof(ushort_t));
    float* el          = (float*)alloc((size_t)N * 4 * sizeof(float));
    float* er          = (float*)alloc((size_t)N * 4 * sizeof(float));
    int*   row_start   = (int*)  alloc(((size_t)N + 1) * sizeof(int));
    int*   csr         = (int*)  alloc((size_t)E * sizeof(int));
    uint*  binned      = (uint*) alloc((size_t)E * sizeof(uint));
    int*   bucketCount = (int*)  alloc(NB_MAX * sizeof(int));
    int*   bucketStart = (int*)  alloc((NB_MAX + 1) * sizeof(int));
    int*   bucketCursor= (int*)  alloc(NB_MAX * sizeof(int));
    ushort_t* wt       = (ushort_t*)alloc((size_t)128 * 128 * sizeof(ushort_t));
    (void)ws_size;

    const int nblkE = (E + EPB - 1) / EPB;   // 782

    hipMemsetAsync(bucketCount, 0, NB_MAX * sizeof(int), stream);

    wt_prep_kernel<<<64, 256, 0, stream>>>(fc_w, wt);
    proj_kernel<<<(N + 63) / 64, 256, 0, stream>>>(x, wt, attn_l, attn_r,
                                                   feat16, el, er, N);
    coarse_hist_kernel<<<nblkE, 256, 0, stream>>>(edst, bucketCount, E, NB);
    bucket_scan_kernel<<<1, 512, 0, stream>>>(bucketCount, bucketStart,
                                              bucketCursor, row_start, NB, N);
    bin_kernel<<<nblkE, 256, 0, stream>>>(esrc, edst, bucketCursor, binned, E, NB);
    fine_csr_kernel<<<NB, 256, 0, stream>>>(binned, bucketStart, row_start, csr, N);
    aggregate_kernel<<<(N + 3) / 4, 256, 0, stream>>>((const uint*)feat16, el, er,
                                                      row_start, csr, bias, out, N);
}

// Round 7
// 182.089 us; speedup vs baseline: 1.3189x; 1.3189x over previous
//
#include <hip/hip_runtime.h>

#define IN_DIM 128
#define HEADS 4
#define OUT_DIM 32
#define NEG 0.2f

#define NPB 256        // nodes per bucket (power of 2; bucket = dst >> 8)
#define NB_MAX 400     // max buckets (N=100000 -> 391)
#define EPB 8192       // edges per block in hist/bin kernels (round-6 showed 2048 regresses)

typedef unsigned int uint;
typedef unsigned short ushort_t;
typedef short short8 __attribute__((ext_vector_type(8)));
typedef float f32x4 __attribute__((ext_vector_type(4)));
typedef uint u32x4 __attribute__((ext_vector_type(4)));

__device__ __forceinline__ uint bf16r(float f) {
    uint u = __float_as_uint(f);
    return (u + 0x7fffu + ((u >> 16) & 1u)) >> 16;   // RNE
}

// ---------------- W^T bf16 prep: wt[n][k] = bf16(W[k][n]) -----------------
__global__ __launch_bounds__(256) void wt_prep_kernel(
    const float* __restrict__ fc_w, ushort_t* __restrict__ wt)
{
    int t = blockIdx.x * 256 + threadIdx.x;   // 64 blocks x 256 = 16384
    int n = t >> 7, k = t & 127;
    wt[t] = (ushort_t)bf16r(fc_w[k * 128 + n]);
}

// ---------------- projection via MFMA (no LDS) ----------------------------
__global__ __launch_bounds__(256) void proj_kernel(
    const float* __restrict__ x, const ushort_t* __restrict__ wt,
    const float* __restrict__ attn_l, const float* __restrict__ attn_r,
    ushort_t* __restrict__ feat16, float* __restrict__ el, float* __restrict__ er,
    int N)
{
    const int lane = threadIdx.x & 63;
    const int w    = threadIdx.x >> 6;
    const int rowbase = blockIdx.x * 64 + w * 16;
    const int c = lane & 15;
    const int g = lane >> 4;

    f32x4 acc[8];
    #pragma unroll
    for (int nt = 0; nt < 8; ++nt) acc[nt] = (f32x4){0.f, 0.f, 0.f, 0.f};

    const int arow  = rowbase + c;
    const int arowc = (arow < N) ? arow : (N - 1);     // clamp OOB reads
    const float* xrow = x + (size_t)arowc * 128 + g * 8;

    #pragma unroll
    for (int kk = 0; kk < 4; ++kk) {
        const float* xp = xrow + kk * 32;
        float4 f0 = *(const float4*)xp;
        float4 f1 = *(const float4*)(xp + 4);
        u32x4 au;
        au.x = bf16r(f0.x) | (bf16r(f0.y) << 16);
        au.y = bf16r(f0.z) | (bf16r(f0.w) << 16);
        au.z = bf16r(f1.x) | (bf16r(f1.y) << 16);
        au.w = bf16r(f1.z) | (bf16r(f1.w) << 16);
        short8 afrag = __builtin_bit_cast(short8, au);
        #pragma unroll
        for (int nt = 0; nt < 8; ++nt) {
            const ushort_t* wp = wt + ((nt * 16 + c) * 128 + kk * 32 + g * 8);
            u32x4 bu = *(const u32x4*)wp;               // 16B aligned
            short8 bfrag = __builtin_bit_cast(short8, bu);
            acc[nt] = __builtin_amdgcn_mfma_f32_16x16x32_bf16(afrag, bfrag, acc[nt], 0, 0, 0);
        }
    }

    float alv[4][2], arv[4][2];
    #pragma unroll
    for (int h = 0; h < 4; ++h) {
        alv[h][0] = attn_l[h * 32 + c];
        alv[h][1] = attn_l[h * 32 + 16 + c];
        arv[h][0] = attn_r[h * 32 + c];
        arv[h][1] = attn_r[h * 32 + 16 + c];
    }

    #pragma unroll
    for (int r = 0; r < 4; ++r) {
        const int node = rowbase + g * 4 + r;
        const bool ok = (node < N);
        ushort_t* fp = feat16 + (size_t)node * 128 + c;
        #pragma unroll
        for (int nt = 0; nt < 8; ++nt) {
            if (ok) fp[nt * 16] = (ushort_t)bf16r(acc[nt][r]);
        }
        #pragma unroll
        for (int h = 0; h < 4; ++h) {
            float accl = acc[2*h][r] * alv[h][0] + acc[2*h+1][r] * alv[h][1];
            float accr = acc[2*h][r] * arv[h][0] + acc[2*h+1][r] * arv[h][1];
            accl += __shfl_xor(accl, 1); accl += __shfl_xor(accl, 2);
            accl += __shfl_xor(accl, 4); accl += __shfl_xor(accl, 8);
            accr += __shfl_xor(accr, 1); accr += __shfl_xor(accr, 2);
            accr += __shfl_xor(accr, 4); accr += __shfl_xor(accr, 8);
            if (ok && c == 0) {
                el[node * 4 + h] = accl;
                er[node * 4 + h] = accr;
            }
        }
    }
}

// ---------------- CSR build: 2-level multisplit ---------------------------
__global__ __launch_bounds__(256) void coarse_hist_kernel(
    const int* __restrict__ edst, int* __restrict__ bucketCount, int E, int NB)
{
    __shared__ int h[NB_MAX];
    for (int t = threadIdx.x; t < NB_MAX; t += 256) h[t] = 0;
    __syncthreads();
    const int base = blockIdx.x * EPB;
    #pragma unroll
    for (int rep = 0; rep < EPB / 1024; ++rep) {
        int i = base + (rep * 256 + threadIdx.x) * 4;
        if (i + 3 < E) {
            int4 d = *(const int4*)(edst + i);
            atomicAdd(&h[d.x >> 8], 1);
            atomicAdd(&h[d.y >> 8], 1);
            atomicAdd(&h[d.z >> 8], 1);
            atomicAdd(&h[d.w >> 8], 1);
        } else {
            for (int k = 0; k < 4; ++k)
                if (i + k < E) atomicAdd(&h[edst[i + k] >> 8], 1);
        }
    }
    __syncthreads();
    for (int t = threadIdx.x; t < NB; t += 256)
        if (h[t]) atomicAdd(&bucketCount[t], h[t]);
}

__global__ __launch_bounds__(512) void bucket_scan_kernel(
    const int* __restrict__ bucketCount, int* __restrict__ bucketStart,
    int* __restrict__ bucketCursor, int* __restrict__ row_start, int NB, int N)
{
    __shared__ int p[512];
    const int t = threadIdx.x;
    int v = (t < NB) ? bucketCount[t] : 0;
    p[t] = v;
    __syncthreads();
    for (int off = 1; off < 512; off <<= 1) {
        int u = (t >= off) ? p[t - off] : 0;
        __syncthreads();
        p[t] += u;
        __syncthreads();
    }
    if (t < NB) {
        bucketStart[t]  = p[t] - v;
        bucketCursor[t] = p[t] - v;
    }
    if (t == NB - 1) {
        bucketStart[NB] = p[t];
        row_start[N]    = p[t];   // == E
    }
}

__global__ __launch_bounds__(256) void bin_kernel(
    const int* __restrict__ esrc, const int* __restrict__ edst,
    int* __restrict__ bucketCursor, uint* __restrict__ binned, int E, int NB)
{
    __shared__ int dstS[EPB];      // 32 KB
    __shared__ int hist[NB_MAX];
    __shared__ int cur[NB_MAX];
    const int t = threadIdx.x;
    for (int k = t; k < NB_MAX; k += 256) hist[k] = 0;
    __syncthreads();

    const int base = blockIdx.x * EPB;
    #pragma unroll
    for (int rep = 0; rep < EPB / 1024; ++rep) {
        int idx4 = (rep * 256 + t) * 4;
        int i = base + idx4;
        if (i + 3 < E) {
            int4 d = *(const int4*)(edst + i);
            dstS[idx4]     = d.x; atomicAdd(&hist[d.x >> 8], 1);
            dstS[idx4 + 1] = d.y; atomicAdd(&hist[d.y >> 8], 1);
            dstS[idx4 + 2] = d.z; atomicAdd(&hist[d.z >> 8], 1);
            dstS[idx4 + 3] = d.w; atomicAdd(&hist[d.w >> 8], 1);
        } else {
            for (int k = 0; k < 4; ++k)
                if (i + k < E) {
                    int dv = edst[i + k];
                    dstS[idx4 + k] = dv;
                    atomicAdd(&hist[dv >> 8], 1);
                }
        }
    }
    __syncthreads();
    for (int k = t; k < NB; k += 256) {
        int hh = hist[k];
        cur[k] = hh ? atomicAdd(&bucketCursor[k], hh) : 0;
    }
    __syncthreads();
    const int nloc = min(EPB, E - base);
    for (int rep = 0; rep < EPB / 256; ++rep) {
        int idx = rep * 256 + t;
        if (idx < nloc) {
            int dv = dstS[idx];
            int pos = atomicAdd(&cur[dv >> 8], 1);
            int src = esrc[base + idx];                  // coalesced re-read
            binned[pos] = (uint)src | ((uint)(dv & 255) << 24);
        }
    }
}

__global__ __launch_bounds__(256) void fine_csr_kernel(
    const uint* __restrict__ binned, const int* __restrict__ bucketStart,
    int* __restrict__ row_start, int* __restrict__ csr, int N)
{
    __shared__ int hist[256], sc[256], cur[256];
    const int b = blockIdx.x;
    const int t = threadIdx.x;
    const int s = bucketStart[b];
    const int e = bucketStart[b + 1];

    hist[t] = 0;
    __syncthreads();
    for (int i = s + t; i < e; i += 256)
        atomicAdd(&hist[binned[i] >> 24], 1);
    __syncthreads();
    sc[t] = hist[t];
    __syncthreads();
    for (int off = 1; off < 256; off <<= 1) {
        int u = (t >= off) ? sc[t - off] : 0;
        __syncthreads();
        sc[t] += u;
        __syncthreads();
    }
    const int excl = s + sc[t] - hist[t];
    const int gn = b * NPB + t;
    if (gn < N) row_start[gn] = excl;
    cur[t] = excl;
    __syncthreads();
    for (int i = s + t; i < e; i += 256) {
        uint v = binned[i];
        int pos = atomicAdd(&cur[v >> 24], 1);
        csr[pos] = (int)(v & 0xFFFFFFu);
    }
}

// ---------------- aggregation: 4 nodes per wave, 16 lanes each ------------
// Lane 16g+ll serves node-slot g; lane holds feats [8*ll, 8*ll+8) as u32x4.
// Per iteration the wave processes 4 edges (one per group): 1 csr load +
// 1 el gather + 1 dwordx4 feat gather (3 VMEM/4 edges, was 2/edge) and the
// e-math runs once for 4 edges. Weight routed head-wise with ONE shfl.
// No runtime-indexed arrays (round-6 scratch lesson), no reduction for s.
__global__ __launch_bounds__(256) void aggregate_kernel(
    const u32x4* __restrict__ feat4, const float* __restrict__ el,
    const float* __restrict__ er, const int* __restrict__ row_start,
    const int* __restrict__ csr, const float* __restrict__ bias,
    float* __restrict__ out, int N)
{
    const int lane = threadIdx.x & 63;
    const int wv   = threadIdx.x >> 6;
    const int ll   = lane & 15;         // lane within group
    const int hsrc = lane & 3;          // head whose el/weight I compute
    const int node = blockIdx.x * 16 + wv * 4 + (lane >> 4);
    if (node >= N) return;

    const int start = row_start[node];
    const int end   = row_start[node + 1];
    const float er_v = er[node * 4 + hsrc];
    const int route = (lane & 48) | ((lane >> 2) & 3);   // lane holding my head's weight

    float r0=0.f,r1=0.f,r2=0.f,r3=0.f,r4=0.f,r5=0.f,r6=0.f,r7=0.f;
    float s = 0.f;

    int u = (start < end) ? csr[start] : 0;
    float ev = el[u * 4 + hsrc];
    for (int idx = start; idx < end; ++idx) {
        // prefetch next edge's u and el (compiler sinks below the fmas)
        const bool more = (idx + 1 < end);
        int un = more ? csr[idx + 1] : 0;
        float evn = more ? el[un * 4 + hsrc] : 0.f;

        float e = ev + er_v;
        e = fmaxf(e, NEG * e);
        float xw = __expf(e);
        s += xw;
        float xe = __shfl(xw, route);
        u32x4 p = feat4[(size_t)u * 16 + ll];
        r0 = fmaf(xe, __uint_as_float(p.x << 16),          r0);
        r1 = fmaf(xe, __uint_as_float(p.x & 0xffff0000u),  r1);
        r2 = fmaf(xe, __uint_as_float(p.y << 16),          r2);
        r3 = fmaf(xe, __uint_as_float(p.y & 0xffff0000u),  r3);
        r4 = fmaf(xe, __uint_as_float(p.z << 16),          r4);
        r5 = fmaf(xe, __uint_as_float(p.z & 0xffff0000u),  r5);
        r6 = fmaf(xe, __uint_as_float(p.w << 16),          r6);
        r7 = fmaf(xe, __uint_as_float(p.w & 0xffff0000u),  r7);
        u = un; ev = evn;
    }

    // normalize by my head's denominator (no reduce: s already complete)
    float sd = __shfl(s, route);
    sd = fmaxf(sd, 1e-16f);
    r0 /= sd; r1 /= sd; r2 /= sd; r3 /= sd;
    r4 /= sd; r5 /= sd; r6 /= sd; r7 /= sd;

    // head mean: lanes 16g + {c, c+4, c+8, c+12} hold same within-head feats
    r0 += __shfl_xor(r0, 4); r0 += __shfl_xor(r0, 8);
    r1 += __shfl_xor(r1, 4); r1 += __shfl_xor(r1, 8);
    r2 += __shfl_xor(r2, 4); r2 += __shfl_xor(r2, 8);
    r3 += __shfl_xor(r3, 4); r3 += __shfl_xor(r3, 8);
    r4 += __shfl_xor(r4, 4); r4 += __shfl_xor(r4, 8);
    r5 += __shfl_xor(r5, 4); r5 += __shfl_xor(r5, 8);
    r6 += __shfl_xor(r6, 4); r6 += __shfl_xor(r6, 8);
    r7 += __shfl_xor(r7, 4); r7 += __shfl_xor(r7, 8);

    if (ll < 4) {
        const int m0 = ll * 8;                 // within-head feat base
        float4 o0, o1;
        o0.x = 0.25f * (r0 + bias[m0]     + bias[32+m0]   + bias[64+m0]   + bias[96+m0]);
        o0.y = 0.25f * (r1 + bias[m0+1]   + bias[33+m0]   + bias[65+m0]   + bias[97+m0]);
        o0.z = 0.25f * (r2 + bias[m0+2]   + bias[34+m0]   + bias[66+m0]   + bias[98+m0]);
        o0.w = 0.25f * (r3 + bias[m0+3]   + bias[35+m0]   + bias[67+m0]   + bias[99+m0]);
        o1.x = 0.25f * (r4 + bias[m0+4]   + bias[36+m0]   + bias[68+m0]   + bias[100+m0]);
        o1.y = 0.25f * (r5 + bias[m0+5]   + bias[37+m0]   + bias[69+m0]   + bias[101+m0]);
        o1.z = 0.25f * (r6 + bias[m0+6]   + bias[38+m0]   + bias[70+m0]   + bias[102+m0]);
        o1.w = 0.25f * (r7 + bias[m0+7]   + bias[39+m0]   + bias[71+m0]   + bias[103+m0]);
        float* op = out + (size_t)node * 32 + m0;
        *(float4*)op       = o0;
        *(float4*)(op + 4) = o1;
    }
}

// ---------------- launch --------------------------------------------------
extern "C" void kernel_launch(void* const* d_in, const int* in_sizes, int n_in,
                              void* d_out, int out_size, void* d_ws, size_t ws_size,
                              hipStream_t stream)
{
    const float* x      = (const float*)d_in[0];
    const int*   esrc   = (const int*)  d_in[1];
    const int*   edst   = (const int*)  d_in[2];
    const float* fc_w   = (const float*)d_in[3];
    const float* attn_l = (const float*)d_in[4];
    const float* attn_r = (const float*)d_in[5];
    const float* bias   = (const float*)d_in[6];
    float* out = (float*)d_out;

    const int N = in_sizes[0] / IN_DIM;   // 100000
    const int E = in_sizes[1];            // 1600000
    const int NB = (N + NPB - 1) / NPB;   // 391

    size_t o = 0;
    char* base = (char*)d_ws;
    auto alloc = [&](size_t bytes) -> void* {
        void* p = base + o;
        o += (bytes + 255) & ~(size_t)255;
        return p;
    };
    ushort_t* feat16   = (ushort_t*)alloc((size_t)N * 128 * sizeof(ushort_t));
    float* el          = (float*)alloc((size_t)N * 4 * sizeof(float));
    float* er          = (float*)alloc((size_t)N * 4 * sizeof(float));
    int*   row_start   = (int*)  alloc(((size_t)N + 1) * sizeof(int));
    int*   csr         = (int*)  alloc((size_t)E * sizeof(int));
    uint*  binned      = (uint*) alloc((size_t)E * sizeof(uint));
    int*   bucketCount = (int*)  alloc(NB_MAX * sizeof(int));
    int*   bucketStart = (int*)  alloc((NB_MAX + 1) * sizeof(int));
    int*   bucketCursor= (int*)  alloc(NB_MAX * sizeof(int));
    ushort_t* wt       = (ushort_t*)alloc((size_t)128 * 128 * sizeof(ushort_t));
    (void)ws_size;

    const int nblkE = (E + EPB - 1) / EPB;   // 196

    hipMemsetAsync(bucketCount, 0, NB_MAX * sizeof(int), stream);

    wt_prep_kernel<<<64, 256, 0, stream>>>(fc_w, wt);
    proj_kernel<<<(N + 63) / 64, 256, 0, stream>>>(x, wt, attn_l, attn_r,
                                                   feat16, el, er, N);
    coarse_hist_kernel<<<nblkE, 256, 0, stream>>>(edst, bucketCount, E, NB);
    bucket_scan_kernel<<<1, 512, 0, stream>>>(bucketCount, bucketStart,
                                              bucketCursor, row_start, NB, N);
    bin_kernel<<<nblkE, 256, 0, stream>>>(esrc, edst, bucketCursor, binned, E, NB);
    fine_csr_kernel<<<NB, 256, 0, stream>>>(binned, bucketStart, row_start, csr, N);
    aggregate_kernel<<<(N + 15) / 16, 256, 0, stream>>>((const u32x4*)feat16, el, er,
                                                        row_start, csr, bias, out, N);
}

// Round 8
// 169.980 us; speedup vs baseline: 1.4128x; 1.0712x over previous
//
#include <hip/hip_runtime.h>

#define IN_DIM 128
#define HEADS 4
#define OUT_DIM 32
#define NEG 0.2f

#define NPB 256        // nodes per bucket (power of 2; bucket = dst >> 8)
#define NB_MAX 400     // max buckets (N=100000 -> 391)
#define EPB 8192       // edges per block in hist/bin kernels (2048 regressed, round 6)

typedef unsigned int uint;
typedef unsigned short ushort_t;
typedef short short8 __attribute__((ext_vector_type(8)));
typedef float f32x4 __attribute__((ext_vector_type(4)));
typedef uint u32x4 __attribute__((ext_vector_type(4)));

__device__ __forceinline__ uint bf16r(float f) {
    uint u = __float_as_uint(f);
    return (u + 0x7fffu + ((u >> 16) & 1u)) >> 16;   // RNE
}

// ---------------- W^T bf16 prep: wt[n][k] = bf16(W[k][n]) -----------------
__global__ __launch_bounds__(256) void wt_prep_kernel(
    const float* __restrict__ fc_w, ushort_t* __restrict__ wt)
{
    int t = blockIdx.x * 256 + threadIdx.x;   // 64 blocks x 256 = 16384
    int n = t >> 7, k = t & 127;
    wt[t] = (ushort_t)bf16r(fc_w[k * 128 + n]);
}

// ---------------- projection via MFMA (no LDS) ----------------------------
__global__ __launch_bounds__(256) void proj_kernel(
    const float* __restrict__ x, const ushort_t* __restrict__ wt,
    const float* __restrict__ attn_l, const float* __restrict__ attn_r,
    ushort_t* __restrict__ feat16, float* __restrict__ el, float* __restrict__ er,
    int N)
{
    const int lane = threadIdx.x & 63;
    const int w    = threadIdx.x >> 6;
    const int rowbase = blockIdx.x * 64 + w * 16;
    const int c = lane & 15;
    const int g = lane >> 4;

    f32x4 acc[8];
    #pragma unroll
    for (int nt = 0; nt < 8; ++nt) acc[nt] = (f32x4){0.f, 0.f, 0.f, 0.f};

    const int arow  = rowbase + c;
    const int arowc = (arow < N) ? arow : (N - 1);     // clamp OOB reads
    const float* xrow = x + (size_t)arowc * 128 + g * 8;

    #pragma unroll
    for (int kk = 0; kk < 4; ++kk) {
        const float* xp = xrow + kk * 32;
        float4 f0 = *(const float4*)xp;
        float4 f1 = *(const float4*)(xp + 4);
        u32x4 au;
        au.x = bf16r(f0.x) | (bf16r(f0.y) << 16);
        au.y = bf16r(f0.z) | (bf16r(f0.w) << 16);
        au.z = bf16r(f1.x) | (bf16r(f1.y) << 16);
        au.w = bf16r(f1.z) | (bf16r(f1.w) << 16);
        short8 afrag = __builtin_bit_cast(short8, au);
        #pragma unroll
        for (int nt = 0; nt < 8; ++nt) {
            const ushort_t* wp = wt + ((nt * 16 + c) * 128 + kk * 32 + g * 8);
            u32x4 bu = *(const u32x4*)wp;               // 16B aligned
            short8 bfrag = __builtin_bit_cast(short8, bu);
            acc[nt] = __builtin_amdgcn_mfma_f32_16x16x32_bf16(afrag, bfrag, acc[nt], 0, 0, 0);
        }
    }

    float alv[4][2], arv[4][2];
    #pragma unroll
    for (int h = 0; h < 4; ++h) {
        alv[h][0] = attn_l[h * 32 + c];
        alv[h][1] = attn_l[h * 32 + 16 + c];
        arv[h][0] = attn_r[h * 32 + c];
        arv[h][1] = attn_r[h * 32 + 16 + c];
    }

    #pragma unroll
    for (int r = 0; r < 4; ++r) {
        const int node = rowbase + g * 4 + r;
        const bool ok = (node < N);
        ushort_t* fp = feat16 + (size_t)node * 128 + c;
        #pragma unroll
        for (int nt = 0; nt < 8; ++nt) {
            if (ok) fp[nt * 16] = (ushort_t)bf16r(acc[nt][r]);
        }
        #pragma unroll
        for (int h = 0; h < 4; ++h) {
            float accl = acc[2*h][r] * alv[h][0] + acc[2*h+1][r] * alv[h][1];
            float accr = acc[2*h][r] * arv[h][0] + acc[2*h+1][r] * arv[h][1];
            accl += __shfl_xor(accl, 1); accl += __shfl_xor(accl, 2);
            accl += __shfl_xor(accl, 4); accl += __shfl_xor(accl, 8);
            accr += __shfl_xor(accr, 1); accr += __shfl_xor(accr, 2);
            accr += __shfl_xor(accr, 4); accr += __shfl_xor(accr, 8);
            if (ok && c == 0) {
                el[node * 4 + h] = accl;
                er[node * 4 + h] = accr;
            }
        }
    }
}

// ---------------- CSR build: 2-level multisplit ---------------------------
__global__ __launch_bounds__(256) void coarse_hist_kernel(
    const int* __restrict__ edst, int* __restrict__ bucketCount, int E, int NB)
{
    __shared__ int h[NB_MAX];
    for (int t = threadIdx.x; t < NB_MAX; t += 256) h[t] = 0;
    __syncthreads();
    const int base = blockIdx.x * EPB;
    #pragma unroll
    for (int rep = 0; rep < EPB / 1024; ++rep) {
        int i = base + (rep * 256 + threadIdx.x) * 4;
        if (i + 3 < E) {
            int4 d = *(const int4*)(edst + i);
            atomicAdd(&h[d.x >> 8], 1);
            atomicAdd(&h[d.y >> 8], 1);
            atomicAdd(&h[d.z >> 8], 1);
            atomicAdd(&h[d.w >> 8], 1);
        } else {
            for (int k = 0; k < 4; ++k)
                if (i + k < E) atomicAdd(&h[edst[i + k] >> 8], 1);
        }
    }
    __syncthreads();
    for (int t = threadIdx.x; t < NB; t += 256)
        if (h[t]) atomicAdd(&bucketCount[t], h[t]);
}

__global__ __launch_bounds__(512) void bucket_scan_kernel(
    const int* __restrict__ bucketCount, int* __restrict__ bucketStart,
    int* __restrict__ bucketCursor, int* __restrict__ row_start, int NB, int N)
{
    __shared__ int p[512];
    const int t = threadIdx.x;
    int v = (t < NB) ? bucketCount[t] : 0;
    p[t] = v;
    __syncthreads();
    for (int off = 1; off < 512; off <<= 1) {
        int u = (t >= off) ? p[t - off] : 0;
        __syncthreads();
        p[t] += u;
        __syncthreads();
    }
    if (t < NB) {
        bucketStart[t]  = p[t] - v;
        bucketCursor[t] = p[t] - v;
    }
    if (t == NB - 1) {
        bucketStart[NB] = p[t];
        row_start[N]    = p[t];   // == E
    }
}

__global__ __launch_bounds__(256) void bin_kernel(
    const int* __restrict__ esrc, const int* __restrict__ edst,
    int* __restrict__ bucketCursor, uint* __restrict__ binned, int E, int NB)
{
    __shared__ int dstS[EPB];      // 32 KB
    __shared__ int hist[NB_MAX];
    __shared__ int cur[NB_MAX];
    const int t = threadIdx.x;
    for (int k = t; k < NB_MAX; k += 256) hist[k] = 0;
    __syncthreads();

    const int base = blockIdx.x * EPB;
    #pragma unroll
    for (int rep = 0; rep < EPB / 1024; ++rep) {
        int idx4 = (rep * 256 + t) * 4;
        int i = base + idx4;
        if (i + 3 < E) {
            int4 d = *(const int4*)(edst + i);
            dstS[idx4]     = d.x; atomicAdd(&hist[d.x >> 8], 1);
            dstS[idx4 + 1] = d.y; atomicAdd(&hist[d.y >> 8], 1);
            dstS[idx4 + 2] = d.z; atomicAdd(&hist[d.z >> 8], 1);
            dstS[idx4 + 3] = d.w; atomicAdd(&hist[d.w >> 8], 1);
        } else {
            for (int k = 0; k < 4; ++k)
                if (i + k < E) {
                    int dv = edst[i + k];
                    dstS[idx4 + k] = dv;
                    atomicAdd(&hist[dv >> 8], 1);
                }
        }
    }
    __syncthreads();
    for (int k = t; k < NB; k += 256) {
        int hh = hist[k];
        cur[k] = hh ? atomicAdd(&bucketCursor[k], hh) : 0;
    }
    __syncthreads();
    const int nloc = min(EPB, E - base);
    for (int rep = 0; rep < EPB / 256; ++rep) {
        int idx = rep * 256 + t;
        if (idx < nloc) {
            int dv = dstS[idx];
            int pos = atomicAdd(&cur[dv >> 8], 1);
            int src = esrc[base + idx];                  // coalesced re-read
            binned[pos] = (uint)src | ((uint)(dv & 255) << 24);
        }
    }
}

__global__ __launch_bounds__(256) void fine_csr_kernel(
    const uint* __restrict__ binned, const int* __restrict__ bucketStart,
    int* __restrict__ row_start, int* __restrict__ csr, int N)
{
    __shared__ int hist[256], sc[256], cur[256];
    const int b = blockIdx.x;
    const int t = threadIdx.x;
    const int s = bucketStart[b];
    const int e = bucketStart[b + 1];

    hist[t] = 0;
    __syncthreads();
    for (int i = s + t; i < e; i += 256)
        atomicAdd(&hist[binned[i] >> 24], 1);
    __syncthreads();
    sc[t] = hist[t];
    __syncthreads();
    for (int off = 1; off < 256; off <<= 1) {
        int u = (t >= off) ? sc[t - off] : 0;
        __syncthreads();
        sc[t] += u;
        __syncthreads();
    }
    const int excl = s + sc[t] - hist[t];
    const int gn = b * NPB + t;
    if (gn < N) row_start[gn] = excl;
    cur[t] = excl;
    __syncthreads();
    for (int i = s + t; i < e; i += 256) {
        uint v = binned[i];
        int pos = atomicAdd(&cur[v >> 24], 1);
        csr[pos] = (int)(v & 0xFFFFFFu);
    }
}

// ---------------- aggregation: 1 node per wave, 4 edge-slots x 16 octets --
// Lane = (g=lane>>4 edge slot, ll=lane&15 feature octet). Per iteration the
// wave processes 8 edges (2 chunks of 4): 6 VMEM instrs / 8 edges, all
// issued before consumption (deep vmcnt queue). Lane's head h=ll>>2 matches
// its own feats -> NO cross-lane ops in the loop. Uniform loop bounds
// (1 node/wave) -> no divergence. E-math 4x dup (was 16x in round 5).
__global__ __launch_bounds__(256) void aggregate_kernel(
    const u32x4* __restrict__ feat4, const float* __restrict__ el,
    const float* __restrict__ er, const int* __restrict__ row_start,
    const int* __restrict__ csr, const float* __restrict__ bias,
    float* __restrict__ out, int N)
{
    int node = blockIdx.x * 4 + (threadIdx.x >> 6);
    node = __builtin_amdgcn_readfirstlane(node);
    if (node >= N) return;
    const int lane = threadIdx.x & 63;
    const int g  = lane >> 4;        // edge slot 0..3
    const int ll = lane & 15;        // feature octet 0..15
    const int h  = ll >> 2;          // my head

    const int start = row_start[node];
    const int end   = row_start[node + 1];
    const float er_v = er[node * 4 + h];

    float rA0=0.f,rA1=0.f,rA2=0.f,rA3=0.f,rA4=0.f,rA5=0.f,rA6=0.f,rA7=0.f;
    float rB0=0.f,rB1=0.f,rB2=0.f,rB3=0.f,rB4=0.f,rB5=0.f,rB6=0.f,rB7=0.f;
    float sA = 0.f, sB = 0.f;
    const int last = end - 1;

    for (int i0 = start; i0 < end; i0 += 8) {
        const int iA = i0 + g;
        const int iB = i0 + 4 + g;
        const bool vA = iA < end;
        const bool vB = iB < end;
        // issue all 6 loads up front (clamped indices keep OOB slots cheap:
        // they re-fetch the last edge's row -> L1/L2 hit)
        const int uA = csr[vA ? iA : last];
        const int uB = csr[vB ? iB : last];
        float eA = el[uA * 4 + h];
        float eB = el[uB * 4 + h];
        u32x4 pA = feat4[(size_t)uA * 16 + ll];
        u32x4 pB = feat4[(size_t)uB * 16 + ll];

        eA += er_v; eA = fmaxf(eA, NEG * eA);
        float xA = vA ? __expf(eA) : 0.f;
        eB += er_v; eB = fmaxf(eB, NEG * eB);
        float xB = vB ? __expf(eB) : 0.f;
        sA += xA; sB += xB;

        rA0 = fmaf(xA, __uint_as_float(pA.x << 16),         rA0);
        rA1 = fmaf(xA, __uint_as_float(pA.x & 0xffff0000u), rA1);
        rA2 = fmaf(xA, __uint_as_float(pA.y << 16),         rA2);
        rA3 = fmaf(xA, __uint_as_float(pA.y & 0xffff0000u), rA3);
        rA4 = fmaf(xA, __uint_as_float(pA.z << 16),         rA4);
        rA5 = fmaf(xA, __uint_as_float(pA.z & 0xffff0000u), rA5);
        rA6 = fmaf(xA, __uint_as_float(pA.w << 16),         rA6);
        rA7 = fmaf(xA, __uint_as_float(pA.w & 0xffff0000u), rA7);
        rB0 = fmaf(xB, __uint_as_float(pB.x << 16),         rB0);
        rB1 = fmaf(xB, __uint_as_float(pB.x & 0xffff0000u), rB1);
        rB2 = fmaf(xB, __uint_as_float(pB.y << 16),         rB2);
        rB3 = fmaf(xB, __uint_as_float(pB.y & 0xffff0000u), rB3);
        rB4 = fmaf(xB, __uint_as_float(pB.z << 16),         rB4);
        rB5 = fmaf(xB, __uint_as_float(pB.z & 0xffff0000u), rB5);
        rB6 = fmaf(xB, __uint_as_float(pB.w << 16),         rB6);
        rB7 = fmaf(xB, __uint_as_float(pB.w & 0xffff0000u), rB7);
    }

    float r0 = rA0 + rB0, r1 = rA1 + rB1, r2 = rA2 + rB2, r3 = rA3 + rB3;
    float r4 = rA4 + rB4, r5 = rA5 + rB5, r6 = rA6 + rB6, r7 = rA7 + rB7;
    float s = sA + sB;

    // reduce over edge slots g (lane bits 4-5)
    s  += __shfl_xor(s, 16);  s  += __shfl_xor(s, 32);
    r0 += __shfl_xor(r0, 16); r0 += __shfl_xor(r0, 32);
    r1 += __shfl_xor(r1, 16); r1 += __shfl_xor(r1, 32);
    r2 += __shfl_xor(r2, 16); r2 += __shfl_xor(r2, 32);
    r3 += __shfl_xor(r3, 16); r3 += __shfl_xor(r3, 32);
    r4 += __shfl_xor(r4, 16); r4 += __shfl_xor(r4, 32);
    r5 += __shfl_xor(r5, 16); r5 += __shfl_xor(r5, 32);
    r6 += __shfl_xor(r6, 16); r6 += __shfl_xor(r6, 32);
    r7 += __shfl_xor(r7, 16); r7 += __shfl_xor(r7, 32);

    // normalize by my head's denominator
    s = fmaxf(s, 1e-16f);
    r0 /= s; r1 /= s; r2 /= s; r3 /= s;
    r4 /= s; r5 /= s; r6 /= s; r7 /= s;

    // head mean over lane bits 2-3 (h)
    r0 += __shfl_xor(r0, 4); r0 += __shfl_xor(r0, 8);
    r1 += __shfl_xor(r1, 4); r1 += __shfl_xor(r1, 8);
    r2 += __shfl_xor(r2, 4); r2 += __shfl_xor(r2, 8);
    r3 += __shfl_xor(r3, 4); r3 += __shfl_xor(r3, 8);
    r4 += __shfl_xor(r4, 4); r4 += __shfl_xor(r4, 8);
    r5 += __shfl_xor(r5, 4); r5 += __shfl_xor(r5, 8);
    r6 += __shfl_xor(r6, 4); r6 += __shfl_xor(r6, 8);
    r7 += __shfl_xor(r7, 4); r7 += __shfl_xor(r7, 8);

    if (lane < 4) {
        const int m0 = lane * 8;   // within-head feat base (q = ll&3 = lane)
        float4 o0, o1;
        o0.x = 0.25f * (r0 + bias[m0]   + bias[32+m0]   + bias[64+m0]   + bias[96+m0]);
        o0.y = 0.25f * (r1 + bias[m0+1] + bias[33+m0]   + bias[65+m0]   + bias[97+m0]);
        o0.z = 0.25f * (r2 + bias[m0+2] + bias[34+m0]   + bias[66+m0]   + bias[98+m0]);
        o0.w = 0.25f * (r3 + bias[m0+3] + bias[35+m0]   + bias[67+m0]   + bias[99+m0]);
        o1.x = 0.25f * (r4 + bias[m0+4] + bias[36+m0]   + bias[68+m0]   + bias[100+m0]);
        o1.y = 0.25f * (r5 + bias[m0+5] + bias[37+m0]   + bias[69+m0]   + bias[101+m0]);
        o1.z = 0.25f * (r6 + bias[m0+6] + bias[38+m0]   + bias[70+m0]   + bias[102+m0]);
        o1.w = 0.25f * (r7 + bias[m0+7] + bias[39+m0]   + bias[71+m0]   + bias[103+m0]);
        float* op = out + (size_t)node * 32 + m0;
        *(float4*)op       = o0;
        *(float4*)(op + 4) = o1;
    }
}

// ---------------- launch --------------------------------------------------
extern "C" void kernel_launch(void* const* d_in, const int* in_sizes, int n_in,
                              void* d_out, int out_size, void* d_ws, size_t ws_size,
                              hipStream_t stream)
{
    const float* x      = (const float*)d_in[0];
    const int*   esrc   = (const int*)  d_in[1];
    const int*   edst   = (const int*)  d_in[2];
    const float* fc_w   = (const float*)d_in[3];
    const float* attn_l = (const float*)d_in[4];
    const float* attn_r = (const float*)d_in[5];
    const float* bias   = (const float*)d_in[6];
    float* out = (float*)d_out;

    const int N = in_sizes[0] / IN_DIM;   // 100000
    const int E = in_sizes[1];            // 1600000
    const int NB = (N + NPB - 1) / NPB;   // 391

    size_t o = 0;
    char* base = (char*)d_ws;
    auto alloc = [&](size_t bytes) -> void* {
        void* p = base + o;
        o += (bytes + 255) & ~(size_t)255;
        return p;
    };
    ushort_t* feat16   = (ushort_t*)alloc((size_t)N * 128 * sizeof(ushort_t));
    float* el          = (float*)alloc((size_t)N * 4 * sizeof(float));
    float* er          = (float*)alloc((size_t)N * 4 * sizeof(float));
    int*   row_start   = (int*)  alloc(((size_t)N + 1) * sizeof(int));
    int*   csr         = (int*)  alloc((size_t)E * sizeof(int));
    uint*  binned      = (uint*) alloc((size_t)E * sizeof(uint));
    int*   bucketCount = (int*)  alloc(NB_MAX * sizeof(int));
    int*   bucketStart = (int*)  alloc((NB_MAX + 1) * sizeof(int));
    int*   bucketCursor= (int*)  alloc(NB_MAX * sizeof(int));
    ushort_t* wt       = (ushort_t*)alloc((size_t)128 * 128 * sizeof(ushort_t));
    (void)ws_size;

    const int nblkE = (E + EPB - 1) / EPB;   // 196

    hipMemsetAsync(bucketCount, 0, NB_MAX * sizeof(int), stream);

    wt_prep_kernel<<<64, 256, 0, stream>>>(fc_w, wt);
    proj_kernel<<<(N + 63) / 64, 256, 0, stream>>>(x, wt, attn_l, attn_r,
                                                   feat16, el, er, N);
    coarse_hist_kernel<<<nblkE, 256, 0, stream>>>(edst, bucketCount, E, NB);
    bucket_scan_kernel<<<1, 512, 0, stream>>>(bucketCount, bucketStart,
                                              bucketCursor, row_start, NB, N);
    bin_kernel<<<nblkE, 256, 0, stream>>>(esrc, edst, bucketCursor, binned, E, NB);
    fine_csr_kernel<<<NB, 256, 0, stream>>>(binned, bucketStart, row_start, csr, N);
    aggregate_kernel<<<(N + 3) / 4, 256, 0, stream>>>((const u32x4*)feat16, el, er,
                                                      row_start, csr, bias, out, N);
}

// Round 10
// 165.117 us; speedup vs baseline: 1.4544x; 1.0295x over previous
//
#include <hip/hip_runtime.h>

#define IN_DIM 128
#define HEADS 4
#define OUT_DIM 32
#define NEG 0.2f

#define NPB 256        // nodes per bucket (bucket = dst >> 8)
#define NB_MAX 400     // max buckets (N=100000 -> 391)
#define EPB 8192       // edges per block in hist/bin kernels

typedef unsigned int uint;
typedef unsigned short ushort_t;
typedef short short8 __attribute__((ext_vector_type(8)));
typedef float f32x4 __attribute__((ext_vector_type(4)));
typedef uint u32x4 __attribute__((ext_vector_type(4)));

__device__ __forceinline__ uint bf16r(float f) {
    uint u = __float_as_uint(f);
    return (u + 0x7fffu + ((u >> 16) & 1u)) >> 16;   // RNE
}

// ---------------- W^T bf16 prep: wt[n][k] = bf16(W[k][n]) -----------------
__global__ __launch_bounds__(256) void wt_prep_kernel(
    const float* __restrict__ fc_w, ushort_t* __restrict__ wt)
{
    int t = blockIdx.x * 256 + threadIdx.x;   // 64 blocks x 256 = 16384
    int n = t >> 7, k = t & 127;
    wt[t] = (ushort_t)bf16r(fc_w[k * 128 + n]);
}

// ---------------- fused: coarse hist (first nblkE blocks) + MFMA proj -----
// Round-8 bodies verbatim; only the block-partition wrapper is new.
// Hist blocks issue first so their LDS-atomic work hides under proj's fill.
__global__ __launch_bounds__(256) void proj_hist_kernel(
    const float* __restrict__ x, const ushort_t* __restrict__ wt,
    const float* __restrict__ attn_l, const float* __restrict__ attn_r,
    ushort_t* __restrict__ feat16, float* __restrict__ el, float* __restrict__ er,
    int N,
    const int* __restrict__ edst, int* __restrict__ bucketCount, int E, int NB,
    int nblkE)
{
    __shared__ int hbuf[NB_MAX];

    if ((int)blockIdx.x < nblkE) {
        // ---------------- coarse histogram body (round-8 verbatim) -------
        for (int t = threadIdx.x; t < NB_MAX; t += 256) hbuf[t] = 0;
        __syncthreads();
        const int base = blockIdx.x * EPB;
        #pragma unroll
        for (int rep = 0; rep < EPB / 1024; ++rep) {
            int i = base + (rep * 256 + threadIdx.x) * 4;
            if (i + 3 < E) {
                int4 d = *(const int4*)(edst + i);
                atomicAdd(&hbuf[d.x >> 8], 1);
                atomicAdd(&hbuf[d.y >> 8], 1);
                atomicAdd(&hbuf[d.z >> 8], 1);
                atomicAdd(&hbuf[d.w >> 8], 1);
            } else {
                for (int k = 0; k < 4; ++k)
                    if (i + k < E) atomicAdd(&hbuf[edst[i + k] >> 8], 1);
            }
        }
        __syncthreads();
        for (int t = threadIdx.x; t < NB; t += 256)
            if (hbuf[t]) atomicAdd(&bucketCount[t], hbuf[t]);
        return;
    }

    // ---------------- projection body (round-8 verbatim, bf16 stores) ----
    const int pblk = (int)blockIdx.x - nblkE;
    const int lane = threadIdx.x & 63;
    const int w    = threadIdx.x >> 6;
    const int rowbase = pblk * 64 + w * 16;
    const int c = lane & 15;
    const int g = lane >> 4;

    f32x4 acc[8];
    #pragma unroll
    for (int nt = 0; nt < 8; ++nt) acc[nt] = (f32x4){0.f, 0.f, 0.f, 0.f};

    const int arow  = rowbase + c;
    const int arowc = (arow < N) ? arow : (N - 1);     // clamp OOB reads
    const float* xrow = x + (size_t)arowc * 128 + g * 8;

    #pragma unroll
    for (int kk = 0; kk < 4; ++kk) {
        const float* xp = xrow + kk * 32;
        float4 f0 = *(const float4*)xp;
        float4 f1 = *(const float4*)(xp + 4);
        u32x4 au;
        au.x = bf16r(f0.x) | (bf16r(f0.y) << 16);
        au.y = bf16r(f0.z) | (bf16r(f0.w) << 16);
        au.z = bf16r(f1.x) | (bf16r(f1.y) << 16);
        au.w = bf16r(f1.z) | (bf16r(f1.w) << 16);
        short8 afrag = __builtin_bit_cast(short8, au);
        #pragma unroll
        for (int nt = 0; nt < 8; ++nt) {
            const ushort_t* wp = wt + ((nt * 16 + c) * 128 + kk * 32 + g * 8);
            u32x4 bu = *(const u32x4*)wp;               // 16B aligned
            short8 bfrag = __builtin_bit_cast(short8, bu);
            acc[nt] = __builtin_amdgcn_mfma_f32_16x16x32_bf16(afrag, bfrag, acc[nt], 0, 0, 0);
        }
    }

    float alv[4][2], arv[4][2];
    #pragma unroll
    for (int hh = 0; hh < 4; ++hh) {
        alv[hh][0] = attn_l[hh * 32 + c];
        alv[hh][1] = attn_l[hh * 32 + 16 + c];
        arv[hh][0] = attn_r[hh * 32 + c];
        arv[hh][1] = attn_r[hh * 32 + 16 + c];
    }

    #pragma unroll
    for (int r = 0; r < 4; ++r) {
        const int node = rowbase + g * 4 + r;
        const bool ok = (node < N);
        ushort_t* fp = feat16 + (size_t)node * 128 + c;
        #pragma unroll
        for (int nt = 0; nt < 8; ++nt) {
            if (ok) fp[nt * 16] = (ushort_t)bf16r(acc[nt][r]);
        }
        #pragma unroll
        for (int hh = 0; hh < 4; ++hh) {
            float accl = acc[2*hh][r] * alv[hh][0] + acc[2*hh+1][r] * alv[hh][1];
            float accr = acc[2*hh][r] * arv[hh][0] + acc[2*hh+1][r] * arv[hh][1];
            accl += __shfl_xor(accl, 1); accl += __shfl_xor(accl, 2);
            accl += __shfl_xor(accl, 4); accl += __shfl_xor(accl, 8);
            accr += __shfl_xor(accr, 1); accr += __shfl_xor(accr, 2);
            accr += __shfl_xor(accr, 4); accr += __shfl_xor(accr, 8);
            if (ok && c == 0) {
                el[node * 4 + hh] = accl;
                er[node * 4 + hh] = accr;
            }
        }
    }
}

// ---------------- bucket scan ---------------------------------------------
__global__ __launch_bounds__(512) void bucket_scan_kernel(
    const int* __restrict__ bucketCount, int* __restrict__ bucketStart,
    int* __restrict__ bucketCursor, int* __restrict__ row_start, int NB, int N)
{
    __shared__ int p[512];
    const int t = threadIdx.x;
    int v = (t < NB) ? bucketCount[t] : 0;
    p[t] = v;
    __syncthreads();
    for (int off = 1; off < 512; off <<= 1) {
        int u = (t >= off) ? p[t - off] : 0;
        __syncthreads();
        p[t] += u;
        __syncthreads();
    }
    if (t < NB) {
        bucketStart[t]  = p[t] - v;
        bucketCursor[t] = p[t] - v;
    }
    if (t == NB - 1) {
        bucketStart[NB] = p[t];
        row_start[N]    = p[t];   // == E
    }
}

__global__ __launch_bounds__(256) void bin_kernel(
    const int* __restrict__ esrc, const int* __restrict__ edst,
    int* __restrict__ bucketCursor, uint* __restrict__ binned, int E, int NB)
{
    __shared__ int dstS[EPB];      // 32 KB
    __shared__ int hist[NB_MAX];
    __shared__ int cur[NB_MAX];
    const int t = threadIdx.x;
    for (int k = t; k < NB_MAX; k += 256) hist[k] = 0;
    __syncthreads();

    const int base = blockIdx.x * EPB;
    #pragma unroll
    for (int rep = 0; rep < EPB / 1024; ++rep) {
        int idx4 = (rep * 256 + t) * 4;
        int i = base + idx4;
        if (i + 3 < E) {
            int4 d = *(const int4*)(edst + i);
            dstS[idx4]     = d.x; atomicAdd(&hist[d.x >> 8], 1);
            dstS[idx4 + 1] = d.y; atomicAdd(&hist[d.y >> 8], 1);
            dstS[idx4 + 2] = d.z; atomicAdd(&hist[d.z >> 8], 1);
            dstS[idx4 + 3] = d.w; atomicAdd(&hist[d.w >> 8], 1);
        } else {
            for (int k = 0; k < 4; ++k)
                if (i + k < E) {
                    int dv = edst[i + k];
                    dstS[idx4 + k] = dv;
                    atomicAdd(&hist[dv >> 8], 1);
                }
        }
    }
    __syncthreads();
    for (int k = t; k < NB; k += 256) {
        int hh = hist[k];
        cur[k] = hh ? atomicAdd(&bucketCursor[k], hh) : 0;
    }
    __syncthreads();
    const int nloc = min(EPB, E - base);
    for (int rep = 0; rep < EPB / 256; ++rep) {
        int idx = rep * 256 + t;
        if (idx < nloc) {
            int dv = dstS[idx];
            int pos = atomicAdd(&cur[dv >> 8], 1);
            int src = esrc[base + idx];                  // coalesced re-read
            binned[pos] = (uint)src | ((uint)(dv & 255) << 24);
        }
    }
}

__global__ __launch_bounds__(256) void fine_csr_kernel(
    const uint* __restrict__ binned, const int* __restrict__ bucketStart,
    int* __restrict__ row_start, int* __restrict__ csr, int N)
{
    __shared__ int hist[256], sc[256], cur[256];
    const int b = blockIdx.x;
    const int t = threadIdx.x;
    const int s = bucketStart[b];
    const int e = bucketStart[b + 1];

    hist[t] = 0;
    __syncthreads();
    for (int i = s + t; i < e; i += 256)
        atomicAdd(&hist[binned[i] >> 24], 1);
    __syncthreads();
    sc[t] = hist[t];
    __syncthreads();
    for (int off = 1; off < 256; off <<= 1) {
        int u = (t >= off) ? sc[t - off] : 0;
        __syncthreads();
        sc[t] += u;
        __syncthreads();
    }
    const int excl = s + sc[t] - hist[t];
    const int gn = b * NPB + t;
    if (gn < N) row_start[gn] = excl;
    cur[t] = excl;
    __syncthreads();
    for (int i = s + t; i < e; i += 256) {
        uint v = binned[i];
        int pos = atomicAdd(&cur[v >> 24], 1);
        csr[pos] = (int)(v & 0xFFFFFFu);
    }
}

// ---------------- aggregation (round-8 verbatim, bf16 unpack) -------------
__global__ __launch_bounds__(256) void aggregate_kernel(
    const u32x4* __restrict__ feat4, const float* __restrict__ el,
    const float* __restrict__ er, const int* __restrict__ row_start,
    const int* __restrict__ csr, const float* __restrict__ bias,
    float* __restrict__ out, int N)
{
    int node = blockIdx.x * 4 + (threadIdx.x >> 6);
    node = __builtin_amdgcn_readfirstlane(node);
    if (node >= N) return;
    const int lane = threadIdx.x & 63;
    const int g  = lane >> 4;        // edge slot 0..3
    const int ll = lane & 15;        // feature octet 0..15
    const int h  = ll >> 2;          // my head

    const int start = row_start[node];
    const int end   = row_start[node + 1];
    const float er_v = er[node * 4 + h];

    float rA0=0.f,rA1=0.f,rA2=0.f,rA3=0.f,rA4=0.f,rA5=0.f,rA6=0.f,rA7=0.f;
    float rB0=0.f,rB1=0.f,rB2=0.f,rB3=0.f,rB4=0.f,rB5=0.f,rB6=0.f,rB7=0.f;
    float sA = 0.f, sB = 0.f;
    const int last = end - 1;

    for (int i0 = start; i0 < end; i0 += 8) {
        const int iA = i0 + g;
        const int iB = i0 + 4 + g;
        const bool vA = iA < end;
        const bool vB = iB < end;
        const int uA = csr[vA ? iA : last];
        const int uB = csr[vB ? iB : last];
        float eA = el[uA * 4 + h];
        float eB = el[uB * 4 + h];
        u32x4 pA = feat4[(size_t)uA * 16 + ll];
        u32x4 pB = feat4[(size_t)uB * 16 + ll];

        eA += er_v; eA = fmaxf(eA, NEG * eA);
        float xA = vA ? __expf(eA) : 0.f;
        eB += er_v; eB = fmaxf(eB, NEG * eB);
        float xB = vB ? __expf(eB) : 0.f;
        sA += xA; sB += xB;

        rA0 = fmaf(xA, __uint_as_float(pA.x << 16),         rA0);
        rA1 = fmaf(xA, __uint_as_float(pA.x & 0xffff0000u), rA1);
        rA2 = fmaf(xA, __uint_as_float(pA.y << 16),         rA2);
        rA3 = fmaf(xA, __uint_as_float(pA.y & 0xffff0000u), rA3);
        rA4 = fmaf(xA, __uint_as_float(pA.z << 16),         rA4);
        rA5 = fmaf(xA, __uint_as_float(pA.z & 0xffff0000u), rA5);
        rA6 = fmaf(xA, __uint_as_float(pA.w << 16),         rA6);
        rA7 = fmaf(xA, __uint_as_float(pA.w & 0xffff0000u), rA7);
        rB0 = fmaf(xB, __uint_as_float(pB.x << 16),         rB0);
        rB1 = fmaf(xB, __uint_as_float(pB.x & 0xffff0000u), rB1);
        rB2 = fmaf(xB, __uint_as_float(pB.y << 16),         rB2);
        rB3 = fmaf(xB, __uint_as_float(pB.y & 0xffff0000u), rB3);
        rB4 = fmaf(xB, __uint_as_float(pB.z << 16),         rB4);
        rB5 = fmaf(xB, __uint_as_float(pB.z & 0xffff0000u), rB5);
        rB6 = fmaf(xB, __uint_as_float(pB.w << 16),         rB6);
        rB7 = fmaf(xB, __uint_as_float(pB.w & 0xffff0000u), rB7);
    }

    float r0 = rA0 + rB0, r1 = rA1 + rB1, r2 = rA2 + rB2, r3 = rA3 + rB3;
    float r4 = rA4 + rB4, r5 = rA5 + rB5, r6 = rA6 + rB6, r7 = rA7 + rB7;
    float s = sA + sB;

    // reduce over edge slots g (lane bits 4-5)
    s  += __shfl_xor(s, 16);  s  += __shfl_xor(s, 32);
    r0 += __shfl_xor(r0, 16); r0 += __shfl_xor(r0, 32);
    r1 += __shfl_xor(r1, 16); r1 += __shfl_xor(r1, 32);
    r2 += __shfl_xor(r2, 16); r2 += __shfl_xor(r2, 32);
    r3 += __shfl_xor(r3, 16); r3 += __shfl_xor(r3, 32);
    r4 += __shfl_xor(r4, 16); r4 += __shfl_xor(r4, 32);
    r5 += __shfl_xor(r5, 16); r5 += __shfl_xor(r5, 32);
    r6 += __shfl_xor(r6, 16); r6 += __shfl_xor(r6, 32);
    r7 += __shfl_xor(r7, 16); r7 += __shfl_xor(r7, 32);

    // normalize by my head's denominator
    s = fmaxf(s, 1e-16f);
    r0 /= s; r1 /= s; r2 /= s; r3 /= s;
    r4 /= s; r5 /= s; r6 /= s; r7 /= s;

    // head mean over lane bits 2-3 (h)
    r0 += __shfl_xor(r0, 4); r0 += __shfl_xor(r0, 8);
    r1 += __shfl_xor(r1, 4); r1 += __shfl_xor(r1, 8);
    r2 += __shfl_xor(r2, 4); r2 += __shfl_xor(r2, 8);
    r3 += __shfl_xor(r3, 4); r3 += __shfl_xor(r3, 8);
    r4 += __shfl_xor(r4, 4); r4 += __shfl_xor(r4, 8);
    r5 += __shfl_xor(r5, 4); r5 += __shfl_xor(r5, 8);
    r6 += __shfl_xor(r6, 4); r6 += __shfl_xor(r6, 8);
    r7 += __shfl_xor(r7, 4); r7 += __shfl_xor(r7, 8);

    if (lane < 4) {
        const int m0 = lane * 8;   // within-head feat base
        float4 o0, o1;
        o0.x = 0.25f * (r0 + bias[m0]   + bias[32+m0]   + bias[64+m0]   + bias[96+m0]);
        o0.y = 0.25f * (r1 + bias[m0+1] + bias[33+m0]   + bias[65+m0]   + bias[97+m0]);
        o0.z = 0.25f * (r2 + bias[m0+2] + bias[34+m0]   + bias[66+m0]   + bias[98+m0]);
        o0.w = 0.25f * (r3 + bias[m0+3] + bias[35+m0]   + bias[67+m0]   + bias[99+m0]);
        o1.x = 0.25f * (r4 + bias[m0+4] + bias[36+m0]   + bias[68+m0]   + bias[100+m0]);
        o1.y = 0.25f * (r5 + bias[m0+5] + bias[37+m0]   + bias[69+m0]   + bias[101+m0]);
        o1.z = 0.25f * (r6 + bias[m0+6] + bias[38+m0]   + bias[70+m0]   + bias[102+m0]);
        o1.w = 0.25f * (r7 + bias[m0+7] + bias[39+m0]   + bias[71+m0]   + bias[103+m0]);
        float* op = out + (size_t)node * 32 + m0;
        *(float4*)op       = o0;
        *(float4*)(op + 4) = o1;
    }
}

// ---------------- launch --------------------------------------------------
extern "C" void kernel_launch(void* const* d_in, const int* in_sizes, int n_in,
                              void* d_out, int out_size, void* d_ws, size_t ws_size,
                              hipStream_t stream)
{
    const float* x      = (const float*)d_in[0];
    const int*   esrc   = (const int*)  d_in[1];
    const int*   edst   = (const int*)  d_in[2];
    const float* fc_w   = (const float*)d_in[3];
    const float* attn_l = (const float*)d_in[4];
    const float* attn_r = (const float*)d_in[5];
    const float* bias   = (const float*)d_in[6];
    float* out = (float*)d_out;

    const int N = in_sizes[0] / IN_DIM;   // 100000
    const int E = in_sizes[1];            // 1600000
    const int NB = (N + NPB - 1) / NPB;   // 391

    size_t o = 0;
    char* base = (char*)d_ws;
    auto alloc = [&](size_t bytes) -> void* {
        void* p = base + o;
        o += (bytes + 255) & ~(size_t)255;
        return p;
    };
    ushort_t* feat16   = (ushort_t*)alloc((size_t)N * 128 * sizeof(ushort_t));
    float* el          = (float*)alloc((size_t)N * 4 * sizeof(float));
    float* er          = (float*)alloc((size_t)N * 4 * sizeof(float));
    int*   row_start   = (int*)  alloc(((size_t)N + 1) * sizeof(int));
    int*   csr         = (int*)  alloc((size_t)E * sizeof(int));
    uint*  binned      = (uint*) alloc((size_t)E * sizeof(uint));
    int*   bucketCount = (int*)  alloc(NB_MAX * sizeof(int));
    int*   bucketStart = (int*)  alloc((NB_MAX + 1) * sizeof(int));
    int*   bucketCursor= (int*)  alloc(NB_MAX * sizeof(int));
    ushort_t* wt       = (ushort_t*)alloc((size_t)128 * 128 * sizeof(ushort_t));
    (void)ws_size;

    const int nblkE = (E + EPB - 1) / EPB;    // 196
    const int nblkP = (N + 63) / 64;          // 1563

    hipMemsetAsync(bucketCount, 0, NB_MAX * sizeof(int), stream);

    wt_prep_kernel<<<64, 256, 0, stream>>>(fc_w, wt);
    proj_hist_kernel<<<nblkE + nblkP, 256, 0, stream>>>(
        x, wt, attn_l, attn_r, feat16, el, er, N,
        edst, bucketCount, E, NB, nblkE);
    bucket_scan_kernel<<<1, 512, 0, stream>>>(bucketCount, bucketStart,
                                              bucketCursor, row_start, NB, N);
    bin_kernel<<<nblkE, 256, 0, stream>>>(esrc, edst, bucketCursor, binned, E, NB);
    fine_csr_kernel<<<NB, 256, 0, stream>>>(binned, bucketStart, row_start, csr, N);
    aggregate_kernel<<<(N + 3) / 4, 256, 0, stream>>>((const u32x4*)feat16, el, er,
                                                      row_start, csr, bias, out, N);
}

// Round 11
// 164.458 us; speedup vs baseline: 1.4602x; 1.0040x over previous
//
#include <hip/hip_runtime.h>

#define IN_DIM 128
#define HEADS 4
#define OUT_DIM 32
#define NEG 0.2f

#define NPB 256        // nodes per bucket (bucket = dst >> 8)
#define NB_MAX 400     // max buckets (N=100000 -> 391)
#define EPB 8192       // edges per block in hist/bin kernels

typedef unsigned int uint;
typedef unsigned short ushort_t;
typedef short short8 __attribute__((ext_vector_type(8)));
typedef float f32x4 __attribute__((ext_vector_type(4)));
typedef uint u32x4 __attribute__((ext_vector_type(4)));

__device__ __forceinline__ uint bf16r(float f) {
    uint u = __float_as_uint(f);
    return (u + 0x7fffu + ((u >> 16) & 1u)) >> 16;   // RNE
}

// ---------------- W^T bf16 prep + folded attn columns ---------------------
// wt[n][k]  = bf16(W[k][n])                          (128x128)
// wt2[c][k] = bf16( sum_d W[k][32h+d]*a[h][d] )      (16x128; c<4: attn_l
//             head c, c in 4..7: attn_r head c-4, c>=8: zero pad)
// so el[n][h] = x[n] @ wt2[h], er[n][h] = x[n] @ wt2[4+h]  (one extra MFMA
// B-tile in proj -> replaces the 128-shfl epilogue reduction).
__global__ __launch_bounds__(256) void wt_prep_kernel(
    const float* __restrict__ fc_w, const float* __restrict__ attn_l,
    const float* __restrict__ attn_r,
    ushort_t* __restrict__ wt, ushort_t* __restrict__ wt2)
{
    int t = blockIdx.x * 256 + threadIdx.x;   // 64 blocks x 256 = 16384
    int n = t >> 7, k = t & 127;
    wt[t] = (ushort_t)bf16r(fc_w[k * 128 + n]);
    if (t < 2048) {                            // 16 cols x 128 k
        int col = t >> 7;                      // 0..15
        int kk  = t & 127;
        float ssum = 0.f;
        if (col < 8) {
            int h = col & 3;
            const float* av = (col < 4) ? attn_l : attn_r;
            #pragma unroll 8
            for (int d = 0; d < 32; ++d)
                ssum += fc_w[kk * 128 + h * 32 + d] * av[h * 32 + d];
        }
        wt2[col * 128 + kk] = (ushort_t)bf16r(ssum);
    }
}

// ---------------- fused: coarse hist (first nblkE blocks) + MFMA proj -----
__global__ __launch_bounds__(256) void proj_hist_kernel(
    const float* __restrict__ x, const ushort_t* __restrict__ wt,
    const ushort_t* __restrict__ wt2,
    ushort_t* __restrict__ feat16, float* __restrict__ el, float* __restrict__ er,
    int N,
    const int* __restrict__ edst, int* __restrict__ bucketCount, int E, int NB,
    int nblkE)
{
    __shared__ int hbuf[NB_MAX];

    if ((int)blockIdx.x < nblkE) {
        // ---------------- coarse histogram body --------------------------
        for (int t = threadIdx.x; t < NB_MAX; t += 256) hbuf[t] = 0;
        __syncthreads();
        const int base = blockIdx.x * EPB;
        #pragma unroll
        for (int rep = 0; rep < EPB / 1024; ++rep) {
            int i = base + (rep * 256 + threadIdx.x) * 4;
            if (i + 3 < E) {
                int4 d = *(const int4*)(edst + i);
                atomicAdd(&hbuf[d.x >> 8], 1);
                atomicAdd(&hbuf[d.y >> 8], 1);
                atomicAdd(&hbuf[d.z >> 8], 1);
                atomicAdd(&hbuf[d.w >> 8], 1);
            } else {
                for (int k = 0; k < 4; ++k)
                    if (i + k < E) atomicAdd(&hbuf[edst[i + k] >> 8], 1);
            }
        }
        __syncthreads();
        for (int t = threadIdx.x; t < NB; t += 256)
            if (hbuf[t]) atomicAdd(&bucketCount[t], hbuf[t]);
        return;
    }

    // ---------------- projection body (MFMA, no LDS) ----------------------
    const int pblk = (int)blockIdx.x - nblkE;
    const int lane = threadIdx.x & 63;
    const int w    = threadIdx.x >> 6;
    const int rowbase = pblk * 64 + w * 16;
    const int c = lane & 15;
    const int g = lane >> 4;

    f32x4 acc[8];
    #pragma unroll
    for (int nt = 0; nt < 8; ++nt) acc[nt] = (f32x4){0.f, 0.f, 0.f, 0.f};
    f32x4 acc8v = (f32x4){0.f, 0.f, 0.f, 0.f};   // el/er tile

    const int arow  = rowbase + c;
    const int arowc = (arow < N) ? arow : (N - 1);     // clamp OOB reads
    const float* xrow = x + (size_t)arowc * 128 + g * 8;

    #pragma unroll
    for (int kk = 0; kk < 4; ++kk) {
        const float* xp = xrow + kk * 32;
        float4 f0 = *(const float4*)xp;
        float4 f1 = *(const float4*)(xp + 4);
        u32x4 au;
        au.x = bf16r(f0.x) | (bf16r(f0.y) << 16);
        au.y = bf16r(f0.z) | (bf16r(f0.w) << 16);
        au.z = bf16r(f1.x) | (bf16r(f1.y) << 16);
        au.w = bf16r(f1.z) | (bf16r(f1.w) << 16);
        short8 afrag = __builtin_bit_cast(short8, au);
        #pragma unroll
        for (int nt = 0; nt < 8; ++nt) {
            const ushort_t* wp = wt + ((nt * 16 + c) * 128 + kk * 32 + g * 8);
            u32x4 bu = *(const u32x4*)wp;               // 16B aligned
            short8 bfrag = __builtin_bit_cast(short8, bu);
            acc[nt] = __builtin_amdgcn_mfma_f32_16x16x32_bf16(afrag, bfrag, acc[nt], 0, 0, 0);
        }
        // el/er tile: B = wt2[c][k]
        {
            const ushort_t* wp2 = wt2 + (c * 128 + kk * 32 + g * 8);
            u32x4 bu2 = *(const u32x4*)wp2;
            short8 bfrag2 = __builtin_bit_cast(short8, bu2);
            acc8v = __builtin_amdgcn_mfma_f32_16x16x32_bf16(afrag, bfrag2, acc8v, 0, 0, 0);
        }
    }

    #pragma unroll
    for (int r = 0; r < 4; ++r) {
        const int node = rowbase + g * 4 + r;
        if (node < N) {
            ushort_t* fp = feat16 + (size_t)node * 128 + c;
            #pragma unroll
            for (int nt = 0; nt < 8; ++nt) {
                fp[nt * 16] = (ushort_t)bf16r(acc[nt][r]);
            }
            // D[row=g*4+r][col=c]: col<4 -> el head c; col 4..7 -> er head c-4
            if (c < 4)       el[node * 4 + c]       = acc8v[r];
            else if (c < 8)  er[node * 4 + (c - 4)] = acc8v[r];
        }
    }
}

// ---------------- bucket scan ---------------------------------------------
__global__ __launch_bounds__(512) void bucket_scan_kernel(
    const int* __restrict__ bucketCount, int* __restrict__ bucketStart,
    int* __restrict__ bucketCursor, int* __restrict__ row_start, int NB, int N)
{
    __shared__ int p[512];
    const int t = threadIdx.x;
    int v = (t < NB) ? bucketCount[t] : 0;
    p[t] = v;
    __syncthreads();
    for (int off = 1; off < 512; off <<= 1) {
        int u = (t >= off) ? p[t - off] : 0;
        __syncthreads();
        p[t] += u;
        __syncthreads();
    }
    if (t < NB) {
        bucketStart[t]  = p[t] - v;
        bucketCursor[t] = p[t] - v;
    }
    if (t == NB - 1) {
        bucketStart[NB] = p[t];
        row_start[N]    = p[t];   // == E
    }
}

__global__ __launch_bounds__(256) void bin_kernel(
    const int* __restrict__ esrc, const int* __restrict__ edst,
    int* __restrict__ bucketCursor, uint* __restrict__ binned, int E, int NB)
{
    __shared__ int dstS[EPB];      // 32 KB
    __shared__ int hist[NB_MAX];
    __shared__ int cur[NB_MAX];
    const int t = threadIdx.x;
    for (int k = t; k < NB_MAX; k += 256) hist[k] = 0;
    __syncthreads();

    const int base = blockIdx.x * EPB;
    #pragma unroll
    for (int rep = 0; rep < EPB / 1024; ++rep) {
        int idx4 = (rep * 256 + t) * 4;
        int i = base + idx4;
        if (i + 3 < E) {
            int4 d = *(const int4*)(edst + i);
            dstS[idx4]     = d.x; atomicAdd(&hist[d.x >> 8], 1);
            dstS[idx4 + 1] = d.y; atomicAdd(&hist[d.y >> 8], 1);
            dstS[idx4 + 2] = d.z; atomicAdd(&hist[d.z >> 8], 1);
            dstS[idx4 + 3] = d.w; atomicAdd(&hist[d.w >> 8], 1);
        } else {
            for (int k = 0; k < 4; ++k)
                if (i + k < E) {
                    int dv = edst[i + k];
                    dstS[idx4 + k] = dv;
                    atomicAdd(&hist[dv >> 8], 1);
                }
        }
    }
    __syncthreads();
    for (int k = t; k < NB; k += 256) {
        int hh = hist[k];
        cur[k] = hh ? atomicAdd(&bucketCursor[k], hh) : 0;
    }
    __syncthreads();
    const int nloc = min(EPB, E - base);
    for (int rep = 0; rep < EPB / 256; ++rep) {
        int idx = rep * 256 + t;
        if (idx < nloc) {
            int dv = dstS[idx];
            int pos = atomicAdd(&cur[dv >> 8], 1);
            int src = esrc[base + idx];                  // coalesced re-read
            binned[pos] = (uint)src | ((uint)(dv & 255) << 24);
        }
    }
}

__global__ __launch_bounds__(256) void fine_csr_kernel(
    const uint* __restrict__ binned, const int* __restrict__ bucketStart,
    int* __restrict__ row_start, int* __restrict__ csr, int N)
{
    __shared__ int hist[256], sc[256], cur[256];
    const int b = blockIdx.x;
    const int t = threadIdx.x;
    const int s = bucketStart[b];
    const int e = bucketStart[b + 1];

    hist[t] = 0;
    __syncthreads();
    for (int i = s + t; i < e; i += 256)
        atomicAdd(&hist[binned[i] >> 24], 1);
    __syncthreads();
    sc[t] = hist[t];
    __syncthreads();
    for (int off = 1; off < 256; off <<= 1) {
        int u = (t >= off) ? sc[t - off] : 0;
        __syncthreads();
        sc[t] += u;
        __syncthreads();
    }
    const int excl = s + sc[t] - hist[t];
    const int gn = b * NPB + t;
    if (gn < N) row_start[gn] = excl;
    cur[t] = excl;
    __syncthreads();
    for (int i = s + t; i < e; i += 256) {
        uint v = binned[i];
        int pos = atomicAdd(&cur[v >> 24], 1);
        csr[pos] = (int)(v & 0xFFFFFFu);
    }
}

// ---------------- aggregation (proven round-8 body, bf16 unpack) ----------
__global__ __launch_bounds__(256) void aggregate_kernel(
    const u32x4* __restrict__ feat4, const float* __restrict__ el,
    const float* __restrict__ er, const int* __restrict__ row_start,
    const int* __restrict__ csr, const float* __restrict__ bias,
    float* __restrict__ out, int N)
{
    int node = blockIdx.x * 4 + (threadIdx.x >> 6);
    node = __builtin_amdgcn_readfirstlane(node);
    if (node >= N) return;
    const int lane = threadIdx.x & 63;
    const int g  = lane >> 4;        // edge slot 0..3
    const int ll = lane & 15;        // feature octet 0..15
    const int h  = ll >> 2;          // my head

    const int start = row_start[node];
    const int end   = row_start[node + 1];
    const float er_v = er[node * 4 + h];

    float rA0=0.f,rA1=0.f,rA2=0.f,rA3=0.f,rA4=0.f,rA5=0.f,rA6=0.f,rA7=0.f;
    float rB0=0.f,rB1=0.f,rB2=0.f,rB3=0.f,rB4=0.f,rB5=0.f,rB6=0.f,rB7=0.f;
    float sA = 0.f, sB = 0.f;
    const int last = end - 1;

    for (int i0 = start; i0 < end; i0 += 8) {
        const int iA = i0 + g;
        const int iB = i0 + 4 + g;
        const bool vA = iA < end;
        const bool vB = iB < end;
        const int uA = csr[vA ? iA : last];
        const int uB = csr[vB ? iB : last];
        float eA = el[uA * 4 + h];
        float eB = el[uB * 4 + h];
        u32x4 pA = feat4[(size_t)uA * 16 + ll];
        u32x4 pB = feat4[(size_t)uB * 16 + ll];

        eA += er_v; eA = fmaxf(eA, NEG * eA);
        float xA = vA ? __expf(eA) : 0.f;
        eB += er_v; eB = fmaxf(eB, NEG * eB);
        float xB = vB ? __expf(eB) : 0.f;
        sA += xA; sB += xB;

        rA0 = fmaf(xA, __uint_as_float(pA.x << 16),         rA0);
        rA1 = fmaf(xA, __uint_as_float(pA.x & 0xffff0000u), rA1);
        rA2 = fmaf(xA, __uint_as_float(pA.y << 16),         rA2);
        rA3 = fmaf(xA, __uint_as_float(pA.y & 0xffff0000u), rA3);
        rA4 = fmaf(xA, __uint_as_float(pA.z << 16),         rA4);
        rA5 = fmaf(xA, __uint_as_float(pA.z & 0xffff0000u), rA5);
        rA6 = fmaf(xA, __uint_as_float(pA.w << 16),         rA6);
        rA7 = fmaf(xA, __uint_as_float(pA.w & 0xffff0000u), rA7);
        rB0 = fmaf(xB, __uint_as_float(pB.x << 16),         rB0);
        rB1 = fmaf(xB, __uint_as_float(pB.x & 0xffff0000u), rB1);
        rB2 = fmaf(xB, __uint_as_float(pB.y << 16),         rB2);
        rB3 = fmaf(xB, __uint_as_float(pB.y & 0xffff0000u), rB3);
        rB4 = fmaf(xB, __uint_as_float(pB.z << 16),         rB4);
        rB5 = fmaf(xB, __uint_as_float(pB.z & 0xffff0000u), rB5);
        rB6 = fmaf(xB, __uint_as_float(pB.w << 16),         rB6);
        rB7 = fmaf(xB, __uint_as_float(pB.w & 0xffff0000u), rB7);
    }

    float r0 = rA0 + rB0, r1 = rA1 + rB1, r2 = rA2 + rB2, r3 = rA3 + rB3;
    float r4 = rA4 + rB4, r5 = rA5 + rB5, r6 = rA6 + rB6, r7 = rA7 + rB7;
    float s = sA + sB;

    // reduce over edge slots g (lane bits 4-5)
    s  += __shfl_xor(s, 16);  s  += __shfl_xor(s, 32);
    r0 += __shfl_xor(r0, 16); r0 += __shfl_xor(r0, 32);
    r1 += __shfl_xor(r1, 16); r1 += __shfl_xor(r1, 32);
    r2 += __shfl_xor(r2, 16); r2 += __shfl_xor(r2, 32);
    r3 += __shfl_xor(r3, 16); r3 += __shfl_xor(r3, 32);
    r4 += __shfl_xor(r4, 16); r4 += __shfl_xor(r4, 32);
    r5 += __shfl_xor(r5, 16); r5 += __shfl_xor(r5, 32);
    r6 += __shfl_xor(r6, 16); r6 += __shfl_xor(r6, 32);
    r7 += __shfl_xor(r7, 16); r7 += __shfl_xor(r7, 32);

    // normalize by my head's denominator
    s = fmaxf(s, 1e-16f);
    r0 /= s; r1 /= s; r2 /= s; r3 /= s;
    r4 /= s; r5 /= s; r6 /= s; r7 /= s;

    // head mean over lane bits 2-3 (h)
    r0 += __shfl_xor(r0, 4); r0 += __shfl_xor(r0, 8);
    r1 += __shfl_xor(r1, 4); r1 += __shfl_xor(r1, 8);
    r2 += __shfl_xor(r2, 4); r2 += __shfl_xor(r2, 8);
    r3 += __shfl_xor(r3, 4); r3 += __shfl_xor(r3, 8);
    r4 += __shfl_xor(r4, 4); r4 += __shfl_xor(r4, 8);
    r5 += __shfl_xor(r5, 4); r5 += __shfl_xor(r5, 8);
    r6 += __shfl_xor(r6, 4); r6 += __shfl_xor(r6, 8);
    r7 += __shfl_xor(r7, 4); r7 += __shfl_xor(r7, 8);

    if (lane < 4) {
        const int m0 = lane * 8;   // within-head feat base
        float4 o0, o1;
        o0.x = 0.25f * (r0 + bias[m0]   + bias[32+m0]   + bias[64+m0]   + bias[96+m0]);
        o0.y = 0.25f * (r1 + bias[m0+1] + bias[33+m0]   + bias[65+m0]   + bias[97+m0]);
        o0.z = 0.25f * (r2 + bias[m0+2] + bias[34+m0]   + bias[66+m0]   + bias[98+m0]);
        o0.w = 0.25f * (r3 + bias[m0+3] + bias[35+m0]   + bias[67+m0]   + bias[99+m0]);
        o1.x = 0.25f * (r4 + bias[m0+4] + bias[36+m0]   + bias[68+m0]   + bias[100+m0]);
        o1.y = 0.25f * (r5 + bias[m0+5] + bias[37+m0]   + bias[69+m0]   + bias[101+m0]);
        o1.z = 0.25f * (r6 + bias[m0+6] + bias[38+m0]   + bias[70+m0]   + bias[102+m0]);
        o1.w = 0.25f * (r7 + bias[m0+7] + bias[39+m0]   + bias[71+m0]   + bias[103+m0]);
        float* op = out + (size_t)node * 32 + m0;
        *(float4*)op       = o0;
        *(float4*)(op + 4) = o1;
    }
}

// ---------------- launch --------------------------------------------------
extern "C" void kernel_launch(void* const* d_in, const int* in_sizes, int n_in,
                              void* d_out, int out_size, void* d_ws, size_t ws_size,
                              hipStream_t stream)
{
    const float* x      = (const float*)d_in[0];
    const int*   esrc   = (const int*)  d_in[1];
    const int*   edst   = (const int*)  d_in[2];
    const float* fc_w   = (const float*)d_in[3];
    const float* attn_l = (const float*)d_in[4];
    const float* attn_r = (const float*)d_in[5];
    const float* bias   = (const float*)d_in[6];
    float* out = (float*)d_out;

    const int N = in_sizes[0] / IN_DIM;   // 100000
    const int E = in_sizes[1];            // 1600000
    const int NB = (N + NPB - 1) / NPB;   // 391

    size_t o = 0;
    char* base = (char*)d_ws;
    auto alloc = [&](size_t bytes) -> void* {
        void* p = base + o;
        o += (bytes + 255) & ~(size_t)255;
        return p;
    };
    ushort_t* feat16   = (ushort_t*)alloc((size_t)N * 128 * sizeof(ushort_t));
    float* el          = (float*)alloc((size_t)N * 4 * sizeof(float));
    float* er          = (float*)alloc((size_t)N * 4 * sizeof(float));
    int*   row_start   = (int*)  alloc(((size_t)N + 1) * sizeof(int));
    int*   csr         = (int*)  alloc((size_t)E * sizeof(int));
    uint*  binned      = (uint*) alloc((size_t)E * sizeof(uint));
    int*   bucketCount = (int*)  alloc(NB_MAX * sizeof(int));
    int*   bucketStart = (int*)  alloc((NB_MAX + 1) * sizeof(int));
    int*   bucketCursor= (int*)  alloc(NB_MAX * sizeof(int));
    ushort_t* wt       = (ushort_t*)alloc((size_t)128 * 128 * sizeof(ushort_t));
    ushort_t* wt2      = (ushort_t*)alloc((size_t)16 * 128 * sizeof(ushort_t));
    (void)ws_size;

    const int nblkE = (E + EPB - 1) / EPB;    // 196
    const int nblkP = (N + 63) / 64;          // 1563

    hipMemsetAsync(bucketCount, 0, NB_MAX * sizeof(int), stream);

    wt_prep_kernel<<<64, 256, 0, stream>>>(fc_w, attn_l, attn_r, wt, wt2);
    proj_hist_kernel<<<nblkE + nblkP, 256, 0, stream>>>(
        x, wt, wt2, feat16, el, er, N,
        edst, bucketCount, E, NB, nblkE);
    bucket_scan_kernel<<<1, 512, 0, stream>>>(bucketCount, bucketStart,
                                              bucketCursor, row_start, NB, N);
    bin_kernel<<<nblkE, 256, 0, stream>>>(esrc, edst, bucketCursor, binned, E, NB);
    fine_csr_kernel<<<NB, 256, 0, stream>>>(binned, bucketStart, row_start, csr, N);
    aggregate_kernel<<<(N + 3) / 4, 256, 0, stream>>>((const u32x4*)feat16, el, er,
                                                      row_start, csr, bias, out, N);
}

// Round 12
// 162.145 us; speedup vs baseline: 1.4811x; 1.0143x over previous
//
#include <hip/hip_runtime.h>

#define IN_DIM 128
#define HEADS 4
#define OUT_DIM 32
#define NEG 0.2f

#define NPB 256        // nodes per bucket (bucket = dst >> 8)
#define NB_MAX 400     // max buckets (N=100000 -> 391)
#define EPB 8192       // edges per block in hist/bin kernels

typedef unsigned int uint;
typedef unsigned short ushort_t;
typedef short short8 __attribute__((ext_vector_type(8)));
typedef float f32x4 __attribute__((ext_vector_type(4)));
typedef uint u32x4 __attribute__((ext_vector_type(4)));

__device__ __forceinline__ uint bf16r(float f) {
    uint u = __float_as_uint(f);
    return (u + 0x7fffu + ((u >> 16) & 1u)) >> 16;   // RNE
}

// ---------------- proj body (round-11 verbatim, parameterized block) ------
__device__ __forceinline__ void proj_body(
    int pblk, const float* __restrict__ x, const ushort_t* __restrict__ wt,
    const ushort_t* __restrict__ wt2,
    ushort_t* __restrict__ feat16, float* __restrict__ el, float* __restrict__ er,
    int N)
{
    const int lane = threadIdx.x & 63;
    const int w    = threadIdx.x >> 6;
    const int rowbase = pblk * 64 + w * 16;
    const int c = lane & 15;
    const int g = lane >> 4;

    f32x4 acc[8];
    #pragma unroll
    for (int nt = 0; nt < 8; ++nt) acc[nt] = (f32x4){0.f, 0.f, 0.f, 0.f};
    f32x4 acc8v = (f32x4){0.f, 0.f, 0.f, 0.f};   // el/er tile

    const int arow  = rowbase + c;
    const int arowc = (arow < N) ? arow : (N - 1);     // clamp OOB reads
    const float* xrow = x + (size_t)arowc * 128 + g * 8;

    #pragma unroll
    for (int kk = 0; kk < 4; ++kk) {
        const float* xp = xrow + kk * 32;
        float4 f0 = *(const float4*)xp;
        float4 f1 = *(const float4*)(xp + 4);
        u32x4 au;
        au.x = bf16r(f0.x) | (bf16r(f0.y) << 16);
        au.y = bf16r(f0.z) | (bf16r(f0.w) << 16);
        au.z = bf16r(f1.x) | (bf16r(f1.y) << 16);
        au.w = bf16r(f1.z) | (bf16r(f1.w) << 16);
        short8 afrag = __builtin_bit_cast(short8, au);
        #pragma unroll
        for (int nt = 0; nt < 8; ++nt) {
            const ushort_t* wp = wt + ((nt * 16 + c) * 128 + kk * 32 + g * 8);
            u32x4 bu = *(const u32x4*)wp;               // 16B aligned
            short8 bfrag = __builtin_bit_cast(short8, bu);
            acc[nt] = __builtin_amdgcn_mfma_f32_16x16x32_bf16(afrag, bfrag, acc[nt], 0, 0, 0);
        }
        {
            const ushort_t* wp2 = wt2 + (c * 128 + kk * 32 + g * 8);
            u32x4 bu2 = *(const u32x4*)wp2;
            short8 bfrag2 = __builtin_bit_cast(short8, bu2);
            acc8v = __builtin_amdgcn_mfma_f32_16x16x32_bf16(afrag, bfrag2, acc8v, 0, 0, 0);
        }
    }

    #pragma unroll
    for (int r = 0; r < 4; ++r) {
        const int node = rowbase + g * 4 + r;
        if (node < N) {
            ushort_t* fp = feat16 + (size_t)node * 128 + c;
            #pragma unroll
            for (int nt = 0; nt < 8; ++nt) {
                fp[nt * 16] = (ushort_t)bf16r(acc[nt][r]);
            }
            if (c < 4)       el[node * 4 + c]       = acc8v[r];
            else if (c < 8)  er[node * 4 + (c - 4)] = acc8v[r];
        }
    }
}

// ---------------- k1: wt prep (blocks 0..63) + coarse hist (rest) ---------
__global__ __launch_bounds__(256) void prep_hist_kernel(
    const float* __restrict__ fc_w, const float* __restrict__ attn_l,
    const float* __restrict__ attn_r,
    ushort_t* __restrict__ wt, ushort_t* __restrict__ wt2,
    const int* __restrict__ edst, int* __restrict__ bucketCount, int E, int NB)
{
    __shared__ int hbuf[NB_MAX];

    if (blockIdx.x < 64) {
        int t = blockIdx.x * 256 + threadIdx.x;   // 16384
        int n = t >> 7, k = t & 127;
        wt[t] = (ushort_t)bf16r(fc_w[k * 128 + n]);
        if (t < 2048) {                            // 16 cols x 128 k
            int col = t >> 7;
            int kk  = t & 127;
            float ssum = 0.f;
            if (col < 8) {
                int h = col & 3;
                const float* av = (col < 4) ? attn_l : attn_r;
                #pragma unroll 8
                for (int d = 0; d < 32; ++d)
                    ssum += fc_w[kk * 128 + h * 32 + d] * av[h * 32 + d];
            }
            wt2[col * 128 + kk] = (ushort_t)bf16r(ssum);
        }
        return;
    }

    // coarse histogram body
    const int hblk = (int)blockIdx.x - 64;
    for (int t = threadIdx.x; t < NB_MAX; t += 256) hbuf[t] = 0;
    __syncthreads();
    const int base = hblk * EPB;
    #pragma unroll
    for (int rep = 0; rep < EPB / 1024; ++rep) {
        int i = base + (rep * 256 + threadIdx.x) * 4;
        if (i + 3 < E) {
            int4 d = *(const int4*)(edst + i);
            atomicAdd(&hbuf[d.x >> 8], 1);
            atomicAdd(&hbuf[d.y >> 8], 1);
            atomicAdd(&hbuf[d.z >> 8], 1);
            atomicAdd(&hbuf[d.w >> 8], 1);
        } else {
            for (int k = 0; k < 4; ++k)
                if (i + k < E) atomicAdd(&hbuf[edst[i + k] >> 8], 1);
        }
    }
    __syncthreads();
    for (int t = threadIdx.x; t < NB; t += 256)
        if (hbuf[t]) atomicAdd(&bucketCount[t], hbuf[t]);
}

// ---------------- k2: bucket scan -----------------------------------------
__global__ __launch_bounds__(512) void bucket_scan_kernel(
    const int* __restrict__ bucketCount, int* __restrict__ bucketStart,
    int* __restrict__ bucketCursor, int* __restrict__ row_start, int NB, int N)
{
    __shared__ int p[512];
    const int t = threadIdx.x;
    int v = (t < NB) ? bucketCount[t] : 0;
    p[t] = v;
    __syncthreads();
    for (int off = 1; off < 512; off <<= 1) {
        int u = (t >= off) ? p[t - off] : 0;
        __syncthreads();
        p[t] += u;
        __syncthreads();
    }
    if (t < NB) {
        bucketStart[t]  = p[t] - v;
        bucketCursor[t] = p[t] - v;
    }
    if (t == NB - 1) {
        bucketStart[NB] = p[t];
        row_start[N]    = p[t];   // == E
    }
}

// ---------------- k3: bin (blocks < nblkE) + proj part A ------------------
// bin phase 3 re-reads edst from L2 instead of LDS staging (keeps fused
// kernel LDS ~3KB so proj co-resident blocks aren't LDS-capped).
__global__ __launch_bounds__(256) void bin_proj_kernel(
    const int* __restrict__ esrc, const int* __restrict__ edst,
    int* __restrict__ bucketCursor, uint* __restrict__ binned, int E, int NB,
    int nblkE,
    const float* __restrict__ x, const ushort_t* __restrict__ wt,
    const ushort_t* __restrict__ wt2,
    ushort_t* __restrict__ feat16, float* __restrict__ el, float* __restrict__ er,
    int N)
{
    __shared__ int hist[NB_MAX];
    __shared__ int cur[NB_MAX];

    if ((int)blockIdx.x >= nblkE) {
        proj_body((int)blockIdx.x - nblkE, x, wt, wt2, feat16, el, er, N);
        return;
    }

    const int t = threadIdx.x;
    for (int k = t; k < NB_MAX; k += 256) hist[k] = 0;
    __syncthreads();

    const int base = blockIdx.x * EPB;
    // phase 1: LDS bucket histogram
    #pragma unroll
    for (int rep = 0; rep < EPB / 1024; ++rep) {
        int i = base + (rep * 256 + t) * 4;
        if (i + 3 < E) {
            int4 d = *(const int4*)(edst + i);
            atomicAdd(&hist[d.x >> 8], 1);
            atomicAdd(&hist[d.y >> 8], 1);
            atomicAdd(&hist[d.z >> 8], 1);
            atomicAdd(&hist[d.w >> 8], 1);
        } else {
            for (int k = 0; k < 4; ++k)
                if (i + k < E) atomicAdd(&hist[edst[i + k] >> 8], 1);
        }
    }
    __syncthreads();
    // phase 2: reserve contiguous runs
    for (int k = t; k < NB; k += 256) {
        int hh = hist[k];
        cur[k] = hh ? atomicAdd(&bucketCursor[k], hh) : 0;
    }
    __syncthreads();
    // phase 3: scatter (edst re-read, coalesced L2 hit)
    const int nloc = min(EPB, E - base);
    for (int rep = 0; rep < EPB / 256; ++rep) {
        int idx = rep * 256 + t;
        if (idx < nloc) {
            int dv = edst[base + idx];
            int pos = atomicAdd(&cur[dv >> 8], 1);
            int src = esrc[base + idx];
            binned[pos] = (uint)src | ((uint)(dv & 255) << 24);
        }
    }
}

// ---------------- k4: fine CSR (blocks < NB) + proj part B ----------------
__global__ __launch_bounds__(256) void fine_proj_kernel(
    const uint* __restrict__ binned, const int* __restrict__ bucketStart,
    int* __restrict__ row_start, int* __restrict__ csr, int N, int NBb,
    int projOffset,
    const float* __restrict__ x, const ushort_t* __restrict__ wt,
    const ushort_t* __restrict__ wt2,
    ushort_t* __restrict__ feat16, float* __restrict__ el, float* __restrict__ er)
{
    __shared__ int hist[256], sc[256], cur[256];

    if ((int)blockIdx.x >= NBb) {
        proj_body((int)blockIdx.x - NBb + projOffset, x, wt, wt2, feat16, el, er, N);
        return;
    }

    const int b = blockIdx.x;
    const int t = threadIdx.x;
    const int s = bucketStart[b];
    const int e = bucketStart[b + 1];

    hist[t] = 0;
    __syncthreads();
    for (int i = s + t; i < e; i += 256)
        atomicAdd(&hist[binned[i] >> 24], 1);
    __syncthreads();
    sc[t] = hist[t];
    __syncthreads();
    for (int off = 1; off < 256; off <<= 1) {
        int u = (t >= off) ? sc[t - off] : 0;
        __syncthreads();
        sc[t] += u;
        __syncthreads();
    }
    const int excl = s + sc[t] - hist[t];
    const int gn = b * NPB + t;
    if (gn < N) row_start[gn] = excl;
    cur[t] = excl;
    __syncthreads();
    for (int i = s + t; i < e; i += 256) {
        uint v = binned[i];
        int pos = atomicAdd(&cur[v >> 24], 1);
        csr[pos] = (int)(v & 0xFFFFFFu);
    }
}

// ---------------- aggregation (proven round-8 body, unchanged) ------------
__global__ __launch_bounds__(256) void aggregate_kernel(
    const u32x4* __restrict__ feat4, const float* __restrict__ el,
    const float* __restrict__ er, const int* __restrict__ row_start,
    const int* __restrict__ csr, const float* __restrict__ bias,
    float* __restrict__ out, int N)
{
    int node = blockIdx.x * 4 + (threadIdx.x >> 6);
    node = __builtin_amdgcn_readfirstlane(node);
    if (node >= N) return;
    const int lane = threadIdx.x & 63;
    const int g  = lane >> 4;        // edge slot 0..3
    const int ll = lane & 15;        // feature octet 0..15
    const int h  = ll >> 2;          // my head

    const int start = row_start[node];
    const int end   = row_start[node + 1];
    const float er_v = er[node * 4 + h];

    float rA0=0.f,rA1=0.f,rA2=0.f,rA3=0.f,rA4=0.f,rA5=0.f,rA6=0.f,rA7=0.f;
    float rB0=0.f,rB1=0.f,rB2=0.f,rB3=0.f,rB4=0.f,rB5=0.f,rB6=0.f,rB7=0.f;
    float sA = 0.f, sB = 0.f;
    const int last = end - 1;

    for (int i0 = start; i0 < end; i0 += 8) {
        const int iA = i0 + g;
        const int iB = i0 + 4 + g;
        const bool vA = iA < end;
        const bool vB = iB < end;
        const int uA = csr[vA ? iA : last];
        const int uB = csr[vB ? iB : last];
        float eA = el[uA * 4 + h];
        float eB = el[uB * 4 + h];
        u32x4 pA = feat4[(size_t)uA * 16 + ll];
        u32x4 pB = feat4[(size_t)uB * 16 + ll];

        eA += er_v; eA = fmaxf(eA, NEG * eA);
        float xA = vA ? __expf(eA) : 0.f;
        eB += er_v; eB = fmaxf(eB, NEG * eB);
        float xB = vB ? __expf(eB) : 0.f;
        sA += xA; sB += xB;

        rA0 = fmaf(xA, __uint_as_float(pA.x << 16),         rA0);
        rA1 = fmaf(xA, __uint_as_float(pA.x & 0xffff0000u), rA1);
        rA2 = fmaf(xA, __uint_as_float(pA.y << 16),         rA2);
        rA3 = fmaf(xA, __uint_as_float(pA.y & 0xffff0000u), rA3);
        rA4 = fmaf(xA, __uint_as_float(pA.z << 16),         rA4);
        rA5 = fmaf(xA, __uint_as_float(pA.z & 0xffff0000u), rA5);
        rA6 = fmaf(xA, __uint_as_float(pA.w << 16),         rA6);
        rA7 = fmaf(xA, __uint_as_float(pA.w & 0xffff0000u), rA7);
        rB0 = fmaf(xB, __uint_as_float(pB.x << 16),         rB0);
        rB1 = fmaf(xB, __uint_as_float(pB.x & 0xffff0000u), rB1);
        rB2 = fmaf(xB, __uint_as_float(pB.y << 16),         rB2);
        rB3 = fmaf(xB, __uint_as_float(pB.y & 0xffff0000u), rB3);
        rB4 = fmaf(xB, __uint_as_float(pB.z << 16),         rB4);
        rB5 = fmaf(xB, __uint_as_float(pB.z & 0xffff0000u), rB5);
        rB6 = fmaf(xB, __uint_as_float(pB.w << 16),         rB6);
        rB7 = fmaf(xB, __uint_as_float(pB.w & 0xffff0000u), rB7);
    }

    float r0 = rA0 + rB0, r1 = rA1 + rB1, r2 = rA2 + rB2, r3 = rA3 + rB3;
    float r4 = rA4 + rB4, r5 = rA5 + rB5, r6 = rA6 + rB6, r7 = rA7 + rB7;
    float s = sA + sB;

    // reduce over edge slots g (lane bits 4-5)
    s  += __shfl_xor(s, 16);  s  += __shfl_xor(s, 32);
    r0 += __shfl_xor(r0, 16); r0 += __shfl_xor(r0, 32);
    r1 += __shfl_xor(r1, 16); r1 += __shfl_xor(r1, 32);
    r2 += __shfl_xor(r2, 16); r2 += __shfl_xor(r2, 32);
    r3 += __shfl_xor(r3, 16); r3 += __shfl_xor(r3, 32);
    r4 += __shfl_xor(r4, 16); r4 += __shfl_xor(r4, 32);
    r5 += __shfl_xor(r5, 16); r5 += __shfl_xor(r5, 32);
    r6 += __shfl_xor(r6, 16); r6 += __shfl_xor(r6, 32);
    r7 += __shfl_xor(r7, 16); r7 += __shfl_xor(r7, 32);

    // normalize by my head's denominator
    s = fmaxf(s, 1e-16f);
    float inv = 1.0f / s;
    r0 *= inv; r1 *= inv; r2 *= inv; r3 *= inv;
    r4 *= inv; r5 *= inv; r6 *= inv; r7 *= inv;

    // head mean over lane bits 2-3 (h)
    r0 += __shfl_xor(r0, 4); r0 += __shfl_xor(r0, 8);
    r1 += __shfl_xor(r1, 4); r1 += __shfl_xor(r1, 8);
    r2 += __shfl_xor(r2, 4); r2 += __shfl_xor(r2, 8);
    r3 += __shfl_xor(r3, 4); r3 += __shfl_xor(r3, 8);
    r4 += __shfl_xor(r4, 4); r4 += __shfl_xor(r4, 8);
    r5 += __shfl_xor(r5, 4); r5 += __shfl_xor(r5, 8);
    r6 += __shfl_xor(r6, 4); r6 += __shfl_xor(r6, 8);
    r7 += __shfl_xor(r7, 4); r7 += __shfl_xor(r7, 8);

    if (lane < 4) {
        const int m0 = lane * 8;   // within-head feat base
        float4 o0, o1;
        o0.x = 0.25f * (r0 + bias[m0]   + bias[32+m0]   + bias[64+m0]   + bias[96+m0]);
        o0.y = 0.25f * (r1 + bias[m0+1] + bias[33+m0]   + bias[65+m0]   + bias[97+m0]);
        o0.z = 0.25f * (r2 + bias[m0+2] + bias[34+m0]   + bias[66+m0]   + bias[98+m0]);
        o0.w = 0.25f * (r3 + bias[m0+3] + bias[35+m0]   + bias[67+m0]   + bias[99+m0]);
        o1.x = 0.25f * (r4 + bias[m0+4] + bias[36+m0]   + bias[68+m0]   + bias[100+m0]);
        o1.y = 0.25f * (r5 + bias[m0+5] + bias[37+m0]   + bias[69+m0]   + bias[101+m0]);
        o1.z = 0.25f * (r6 + bias[m0+6] + bias[38+m0]   + bias[70+m0]   + bias[102+m0]);
        o1.w = 0.25f * (r7 + bias[m0+7] + bias[39+m0]   + bias[71+m0]   + bias[103+m0]);
        float* op = out + (size_t)node * 32 + m0;
        *(float4*)op       = o0;
        *(float4*)(op + 4) = o1;
    }
}

// ---------------- launch --------------------------------------------------
extern "C" void kernel_launch(void* const* d_in, const int* in_sizes, int n_in,
                              void* d_out, int out_size, void* d_ws, size_t ws_size,
                              hipStream_t stream)
{
    const float* x      = (const float*)d_in[0];
    const int*   esrc   = (const int*)  d_in[1];
    const int*   edst   = (const int*)  d_in[2];
    const float* fc_w   = (const float*)d_in[3];
    const float* attn_l = (const float*)d_in[4];
    const float* attn_r = (const float*)d_in[5];
    const float* bias   = (const float*)d_in[6];
    float* out = (float*)d_out;

    const int N = in_sizes[0] / IN_DIM;   // 100000
    const int E = in_sizes[1];            // 1600000
    const int NB = (N + NPB - 1) / NPB;   // 391

    size_t o = 0;
    char* base = (char*)d_ws;
    auto alloc = [&](size_t bytes) -> void* {
        void* p = base + o;
        o += (bytes + 255) & ~(size_t)255;
        return p;
    };
    ushort_t* feat16   = (ushort_t*)alloc((size_t)N * 128 * sizeof(ushort_t));
    float* el          = (float*)alloc((size_t)N * 4 * sizeof(float));
    float* er          = (float*)alloc((size_t)N * 4 * sizeof(float));
    int*   row_start   = (int*)  alloc(((size_t)N + 1) * sizeof(int));
    int*   csr         = (int*)  alloc((size_t)E * sizeof(int));
    uint*  binned      = (uint*) alloc((size_t)E * sizeof(uint));
    int*   bucketCount = (int*)  alloc(NB_MAX * sizeof(int));
    int*   bucketStart = (int*)  alloc((NB_MAX + 1) * sizeof(int));
    int*   bucketCursor= (int*)  alloc(NB_MAX * sizeof(int));
    ushort_t* wt       = (ushort_t*)alloc((size_t)128 * 128 * sizeof(ushort_t));
    ushort_t* wt2      = (ushort_t*)alloc((size_t)16 * 128 * sizeof(ushort_t));
    (void)ws_size;

    const int nblkE = (E + EPB - 1) / EPB;    // 196
    const int nblkP = (N + 63) / 64;          // 1563
    const int projA = nblkP / 2;              // 781 blocks in k3
    const int projB = nblkP - projA;          // 782 blocks in k4

    hipMemsetAsync(bucketCount, 0, NB_MAX * sizeof(int), stream);

    prep_hist_kernel<<<64 + nblkE, 256, 0, stream>>>(
        fc_w, attn_l, attn_r, wt, wt2, edst, bucketCount, E, NB);
    bucket_scan_kernel<<<1, 512, 0, stream>>>(bucketCount, bucketStart,
                                              bucketCursor, row_start, NB, N);
    bin_proj_kernel<<<nblkE + projA, 256, 0, stream>>>(
        esrc, edst, bucketCursor, binned, E, NB, nblkE,
        x, wt, wt2, feat16, el, er, N);
    fine_proj_kernel<<<NB + projB, 256, 0, stream>>>(
        binned, bucketStart, row_start, csr, N, NB, projA,
        x, wt, wt2, feat16, el, er);
    aggregate_kernel<<<(N + 3) / 4, 256, 0, stream>>>((const u32x4*)feat16, el, er,
                                                      row_start, csr, bias, out, N);
}

// Round 13
// 150.681 us; speedup vs baseline: 1.5937x; 1.0761x over previous
//
#include <hip/hip_runtime.h>

#define IN_DIM 128
#define HEADS 4
#define OUT_DIM 32
#define NEG 0.2f

#define NPB 256        // nodes per bucket (bucket = dst >> 8)
#define NB_MAX 400     // max buckets (N=100000 -> 391)
#define EPB 8192       // edges per block in hist/bin kernels

typedef unsigned int uint;
typedef unsigned short ushort_t;
typedef short short8 __attribute__((ext_vector_type(8)));
typedef float f32x4 __attribute__((ext_vector_type(4)));
typedef uint u32x4 __attribute__((ext_vector_type(4)));

__device__ __forceinline__ uint bf16r(float f) {
    uint u = __float_as_uint(f);
    return (u + 0x7fffu + ((u >> 16) & 1u)) >> 16;   // RNE
}

// ---------------- proj body: wave = 32 rows (2 A-frags share each B) ------
// B-fragment loads were the bottleneck (44 VMEM/wave for 16 rows, each
// wave re-reading the whole 36KB wt from L2). Two A-tiles per wave reuse
// every B-frag twice: 72 -> 36 B-loads per 32 rows.
__device__ __forceinline__ void proj_body(
    int pblk, const float* __restrict__ x, const ushort_t* __restrict__ wt,
    const ushort_t* __restrict__ wt2,
    ushort_t* __restrict__ feat16, float* __restrict__ el, float* __restrict__ er,
    int N)
{
    const int lane = threadIdx.x & 63;
    const int w    = threadIdx.x >> 6;
    const int rowbase = pblk * 128 + w * 32;   // 32 rows per wave
    const int c = lane & 15;
    const int g = lane >> 4;

    f32x4 acc0[8], acc1[8];
    #pragma unroll
    for (int nt = 0; nt < 8; ++nt) {
        acc0[nt] = (f32x4){0.f, 0.f, 0.f, 0.f};
        acc1[nt] = (f32x4){0.f, 0.f, 0.f, 0.f};
    }
    f32x4 acc8v0 = (f32x4){0.f, 0.f, 0.f, 0.f};   // el/er tile, rows 0..15
    f32x4 acc8v1 = (f32x4){0.f, 0.f, 0.f, 0.f};   // el/er tile, rows 16..31

    const int arow0 = rowbase + c;
    const int arow1 = rowbase + 16 + c;
    const int arow0c = (arow0 < N) ? arow0 : (N - 1);
    const int arow1c = (arow1 < N) ? arow1 : (N - 1);
    const float* xrow0 = x + (size_t)arow0c * 128 + g * 8;
    const float* xrow1 = x + (size_t)arow1c * 128 + g * 8;

    #pragma unroll
    for (int kk = 0; kk < 4; ++kk) {
        float4 a0 = *(const float4*)(xrow0 + kk * 32);
        float4 a1 = *(const float4*)(xrow0 + kk * 32 + 4);
        float4 b0 = *(const float4*)(xrow1 + kk * 32);
        float4 b1 = *(const float4*)(xrow1 + kk * 32 + 4);
        u32x4 au0, au1;
        au0.x = bf16r(a0.x) | (bf16r(a0.y) << 16);
        au0.y = bf16r(a0.z) | (bf16r(a0.w) << 16);
        au0.z = bf16r(a1.x) | (bf16r(a1.y) << 16);
        au0.w = bf16r(a1.z) | (bf16r(a1.w) << 16);
        au1.x = bf16r(b0.x) | (bf16r(b0.y) << 16);
        au1.y = bf16r(b0.z) | (bf16r(b0.w) << 16);
        au1.z = bf16r(b1.x) | (bf16r(b1.y) << 16);
        au1.w = bf16r(b1.z) | (bf16r(b1.w) << 16);
        short8 afrag0 = __builtin_bit_cast(short8, au0);
        short8 afrag1 = __builtin_bit_cast(short8, au1);
        #pragma unroll
        for (int nt = 0; nt < 8; ++nt) {
            const ushort_t* wp = wt + ((nt * 16 + c) * 128 + kk * 32 + g * 8);
            u32x4 bu = *(const u32x4*)wp;               // loaded once...
            short8 bfrag = __builtin_bit_cast(short8, bu);
            acc0[nt] = __builtin_amdgcn_mfma_f32_16x16x32_bf16(afrag0, bfrag, acc0[nt], 0, 0, 0);
            acc1[nt] = __builtin_amdgcn_mfma_f32_16x16x32_bf16(afrag1, bfrag, acc1[nt], 0, 0, 0);  // ...used twice
        }
        {
            const ushort_t* wp2 = wt2 + (c * 128 + kk * 32 + g * 8);
            u32x4 bu2 = *(const u32x4*)wp2;
            short8 bfrag2 = __builtin_bit_cast(short8, bu2);
            acc8v0 = __builtin_amdgcn_mfma_f32_16x16x32_bf16(afrag0, bfrag2, acc8v0, 0, 0, 0);
            acc8v1 = __builtin_amdgcn_mfma_f32_16x16x32_bf16(afrag1, bfrag2, acc8v1, 0, 0, 0);
        }
    }

    #pragma unroll
    for (int r = 0; r < 4; ++r) {
        const int node0 = rowbase + g * 4 + r;
        const int node1 = rowbase + 16 + g * 4 + r;
        if (node0 < N) {
            ushort_t* fp = feat16 + (size_t)node0 * 128 + c;
            #pragma unroll
            for (int nt = 0; nt < 8; ++nt) fp[nt * 16] = (ushort_t)bf16r(acc0[nt][r]);
            if (c < 4)       el[node0 * 4 + c]       = acc8v0[r];
            else if (c < 8)  er[node0 * 4 + (c - 4)] = acc8v0[r];
        }
        if (node1 < N) {
            ushort_t* fp = feat16 + (size_t)node1 * 128 + c;
            #pragma unroll
            for (int nt = 0; nt < 8; ++nt) fp[nt * 16] = (ushort_t)bf16r(acc1[nt][r]);
            if (c < 4)       el[node1 * 4 + c]       = acc8v1[r];
            else if (c < 8)  er[node1 * 4 + (c - 4)] = acc8v1[r];
        }
    }
}

// ---------------- k1: wt prep (blocks 0..63) + coarse hist (rest) ---------
__global__ __launch_bounds__(256) void prep_hist_kernel(
    const float* __restrict__ fc_w, const float* __restrict__ attn_l,
    const float* __restrict__ attn_r,
    ushort_t* __restrict__ wt, ushort_t* __restrict__ wt2,
    const int* __restrict__ edst, int* __restrict__ bucketCount, int E, int NB)
{
    __shared__ int hbuf[NB_MAX];

    if (blockIdx.x < 64) {
        int t = blockIdx.x * 256 + threadIdx.x;   // 16384
        int n = t >> 7, k = t & 127;
        wt[t] = (ushort_t)bf16r(fc_w[k * 128 + n]);
        if (t < 2048) {                            // 16 cols x 128 k
            int col = t >> 7;
            int kk  = t & 127;
            float ssum = 0.f;
            if (col < 8) {
                int h = col & 3;
                const float* av = (col < 4) ? attn_l : attn_r;
                #pragma unroll 8
                for (int d = 0; d < 32; ++d)
                    ssum += fc_w[kk * 128 + h * 32 + d] * av[h * 32 + d];
            }
            wt2[col * 128 + kk] = (ushort_t)bf16r(ssum);
        }
        return;
    }

    const int hblk = (int)blockIdx.x - 64;
    for (int t = threadIdx.x; t < NB_MAX; t += 256) hbuf[t] = 0;
    __syncthreads();
    const int base = hblk * EPB;
    #pragma unroll
    for (int rep = 0; rep < EPB / 1024; ++rep) {
        int i = base + (rep * 256 + threadIdx.x) * 4;
        if (i + 3 < E) {
            int4 d = *(const int4*)(edst + i);
            atomicAdd(&hbuf[d.x >> 8], 1);
            atomicAdd(&hbuf[d.y >> 8], 1);
            atomicAdd(&hbuf[d.z >> 8], 1);
            atomicAdd(&hbuf[d.w >> 8], 1);
        } else {
            for (int k = 0; k < 4; ++k)
                if (i + k < E) atomicAdd(&hbuf[edst[i + k] >> 8], 1);
        }
    }
    __syncthreads();
    for (int t = threadIdx.x; t < NB; t += 256)
        if (hbuf[t]) atomicAdd(&bucketCount[t], hbuf[t]);
}

// ---------------- k2: bucket scan -----------------------------------------
__global__ __launch_bounds__(512) void bucket_scan_kernel(
    const int* __restrict__ bucketCount, int* __restrict__ bucketStart,
    int* __restrict__ bucketCursor, int* __restrict__ row_start, int NB, int N)
{
    __shared__ int p[512];
    const int t = threadIdx.x;
    int v = (t < NB) ? bucketCount[t] : 0;
    p[t] = v;
    __syncthreads();
    for (int off = 1; off < 512; off <<= 1) {
        int u = (t >= off) ? p[t - off] : 0;
        __syncthreads();
        p[t] += u;
        __syncthreads();
    }
    if (t < NB) {
        bucketStart[t]  = p[t] - v;
        bucketCursor[t] = p[t] - v;
    }
    if (t == NB - 1) {
        bucketStart[NB] = p[t];
        row_start[N]    = p[t];   // == E
    }
}

// ---------------- k3: bin (blocks < nblkE) + proj part A ------------------
__global__ __launch_bounds__(256) void bin_proj_kernel(
    const int* __restrict__ esrc, const int* __restrict__ edst,
    int* __restrict__ bucketCursor, uint* __restrict__ binned, int E, int NB,
    int nblkE,
    const float* __restrict__ x, const ushort_t* __restrict__ wt,
    const ushort_t* __restrict__ wt2,
    ushort_t* __restrict__ feat16, float* __restrict__ el, float* __restrict__ er,
    int N)
{
    __shared__ int hist[NB_MAX];
    __shared__ int cur[NB_MAX];

    if ((int)blockIdx.x >= nblkE) {
        proj_body((int)blockIdx.x - nblkE, x, wt, wt2, feat16, el, er, N);
        return;
    }

    const int t = threadIdx.x;
    for (int k = t; k < NB_MAX; k += 256) hist[k] = 0;
    __syncthreads();

    const int base = blockIdx.x * EPB;
    #pragma unroll
    for (int rep = 0; rep < EPB / 1024; ++rep) {
        int i = base + (rep * 256 + t) * 4;
        if (i + 3 < E) {
            int4 d = *(const int4*)(edst + i);
            atomicAdd(&hist[d.x >> 8], 1);
            atomicAdd(&hist[d.y >> 8], 1);
            atomicAdd(&hist[d.z >> 8], 1);
            atomicAdd(&hist[d.w >> 8], 1);
        } else {
            for (int k = 0; k < 4; ++k)
                if (i + k < E) atomicAdd(&hist[edst[i + k] >> 8], 1);
        }
    }
    __syncthreads();
    for (int k = t; k < NB; k += 256) {
        int hh = hist[k];
        cur[k] = hh ? atomicAdd(&bucketCursor[k], hh) : 0;
    }
    __syncthreads();
    const int nloc = min(EPB, E - base);
    for (int rep = 0; rep < EPB / 256; ++rep) {
        int idx = rep * 256 + t;
        if (idx < nloc) {
            int dv = edst[base + idx];
            int pos = atomicAdd(&cur[dv >> 8], 1);
            int src = esrc[base + idx];
            binned[pos] = (uint)src | ((uint)(dv & 255) << 24);
        }
    }
}

// ---------------- k4: fine CSR (blocks < NB) + proj part B ----------------
__global__ __launch_bounds__(256) void fine_proj_kernel(
    const uint* __restrict__ binned, const int* __restrict__ bucketStart,
    int* __restrict__ row_start, int* __restrict__ csr, int N, int NBb,
    int projOffset,
    const float* __restrict__ x, const ushort_t* __restrict__ wt,
    const ushort_t* __restrict__ wt2,
    ushort_t* __restrict__ feat16, float* __restrict__ el, float* __restrict__ er)
{
    __shared__ int hist[256], sc[256], cur[256];

    if ((int)blockIdx.x >= NBb) {
        proj_body((int)blockIdx.x - NBb + projOffset, x, wt, wt2, feat16, el, er, N);
        return;
    }

    const int b = blockIdx.x;
    const int t = threadIdx.x;
    const int s = bucketStart[b];
    const int e = bucketStart[b + 1];

    hist[t] = 0;
    __syncthreads();
    for (int i = s + t; i < e; i += 256)
        atomicAdd(&hist[binned[i] >> 24], 1);
    __syncthreads();
    sc[t] = hist[t];
    __syncthreads();
    for (int off = 1; off < 256; off <<= 1) {
        int u = (t >= off) ? sc[t - off] : 0;
        __syncthreads();
        sc[t] += u;
        __syncthreads();
    }
    const int excl = s + sc[t] - hist[t];
    const int gn = b * NPB + t;
    if (gn < N) row_start[gn] = excl;
    cur[t] = excl;
    __syncthreads();
    for (int i = s + t; i < e; i += 256) {
        uint v = binned[i];
        int pos = atomicAdd(&cur[v >> 24], 1);
        csr[pos] = (int)(v & 0xFFFFFFu);
    }
}

// ---------------- aggregation (proven body, unchanged) --------------------
__global__ __launch_bounds__(256) void aggregate_kernel(
    const u32x4* __restrict__ feat4, const float* __restrict__ el,
    const float* __restrict__ er, const int* __restrict__ row_start,
    const int* __restrict__ csr, const float* __restrict__ bias,
    float* __restrict__ out, int N)
{
    int node = blockIdx.x * 4 + (threadIdx.x >> 6);
    node = __builtin_amdgcn_readfirstlane(node);
    if (node >= N) return;
    const int lane = threadIdx.x & 63;
    const int g  = lane >> 4;        // edge slot 0..3
    const int ll = lane & 15;        // feature octet 0..15
    const int h  = ll >> 2;          // my head

    const int start = row_start[node];
    const int end   = row_start[node + 1];
    const float er_v = er[node * 4 + h];

    float rA0=0.f,rA1=0.f,rA2=0.f,rA3=0.f,rA4=0.f,rA5=0.f,rA6=0.f,rA7=0.f;
    float rB0=0.f,rB1=0.f,rB2=0.f,rB3=0.f,rB4=0.f,rB5=0.f,rB6=0.f,rB7=0.f;
    float sA = 0.f, sB = 0.f;
    const int last = end - 1;

    for (int i0 = start; i0 < end; i0 += 8) {
        const int iA = i0 + g;
        const int iB = i0 + 4 + g;
        const bool vA = iA < end;
        const bool vB = iB < end;
        const int uA = csr[vA ? iA : last];
        const int uB = csr[vB ? iB : last];
        float eA = el[uA * 4 + h];
        float eB = el[uB * 4 + h];
        u32x4 pA = feat4[(size_t)uA * 16 + ll];
        u32x4 pB = feat4[(size_t)uB * 16 + ll];

        eA += er_v; eA = fmaxf(eA, NEG * eA);
        float xA = vA ? __expf(eA) : 0.f;
        eB += er_v; eB = fmaxf(eB, NEG * eB);
        float xB = vB ? __expf(eB) : 0.f;
        sA += xA; sB += xB;

        rA0 = fmaf(xA, __uint_as_float(pA.x << 16),         rA0);
        rA1 = fmaf(xA, __uint_as_float(pA.x & 0xffff0000u), rA1);
        rA2 = fmaf(xA, __uint_as_float(pA.y << 16),         rA2);
        rA3 = fmaf(xA, __uint_as_float(pA.y & 0xffff0000u), rA3);
        rA4 = fmaf(xA, __uint_as_float(pA.z << 16),         rA4);
        rA5 = fmaf(xA, __uint_as_float(pA.z & 0xffff0000u), rA5);
        rA6 = fmaf(xA, __uint_as_float(pA.w << 16),         rA6);
        rA7 = fmaf(xA, __uint_as_float(pA.w & 0xffff0000u), rA7);
        rB0 = fmaf(xB, __uint_as_float(pB.x << 16),         rB0);
        rB1 = fmaf(xB, __uint_as_float(pB.x & 0xffff0000u), rB1);
        rB2 = fmaf(xB, __uint_as_float(pB.y << 16),         rB2);
        rB3 = fmaf(xB, __uint_as_float(pB.y & 0xffff0000u), rB3);
        rB4 = fmaf(xB, __uint_as_float(pB.z << 16),         rB4);
        rB5 = fmaf(xB, __uint_as_float(pB.z & 0xffff0000u), rB5);
        rB6 = fmaf(xB, __uint_as_float(pB.w << 16),         rB6);
        rB7 = fmaf(xB, __uint_as_float(pB.w & 0xffff0000u), rB7);
    }

    float r0 = rA0 + rB0, r1 = rA1 + rB1, r2 = rA2 + rB2, r3 = rA3 + rB3;
    float r4 = rA4 + rB4, r5 = rA5 + rB5, r6 = rA6 + rB6, r7 = rA7 + rB7;
    float s = sA + sB;

    s  += __shfl_xor(s, 16);  s  += __shfl_xor(s, 32);
    r0 += __shfl_xor(r0, 16); r0 += __shfl_xor(r0, 32);
    r1 += __shfl_xor(r1, 16); r1 += __shfl_xor(r1, 32);
    r2 += __shfl_xor(r2, 16); r2 += __shfl_xor(r2, 32);
    r3 += __shfl_xor(r3, 16); r3 += __shfl_xor(r3, 32);
    r4 += __shfl_xor(r4, 16); r4 += __shfl_xor(r4, 32);
    r5 += __shfl_xor(r5, 16); r5 += __shfl_xor(r5, 32);
    r6 += __shfl_xor(r6, 16); r6 += __shfl_xor(r6, 32);
    r7 += __shfl_xor(r7, 16); r7 += __shfl_xor(r7, 32);

    s = fmaxf(s, 1e-16f);
    float inv = 1.0f / s;
    r0 *= inv; r1 *= inv; r2 *= inv; r3 *= inv;
    r4 *= inv; r5 *= inv; r6 *= inv; r7 *= inv;

    r0 += __shfl_xor(r0, 4); r0 += __shfl_xor(r0, 8);
    r1 += __shfl_xor(r1, 4); r1 += __shfl_xor(r1, 8);
    r2 += __shfl_xor(r2, 4); r2 += __shfl_xor(r2, 8);
    r3 += __shfl_xor(r3, 4); r3 += __shfl_xor(r3, 8);
    r4 += __shfl_xor(r4, 4); r4 += __shfl_xor(r4, 8);
    r5 += __shfl_xor(r5, 4); r5 += __shfl_xor(r5, 8);
    r6 += __shfl_xor(r6, 4); r6 += __shfl_xor(r6, 8);
    r7 += __shfl_xor(r7, 4); r7 += __shfl_xor(r7, 8);

    if (lane < 4) {
        const int m0 = lane * 8;
        float4 o0, o1;
        o0.x = 0.25f * (r0 + bias[m0]   + bias[32+m0]   + bias[64+m0]   + bias[96+m0]);
        o0.y = 0.25f * (r1 + bias[m0+1] + bias[33+m0]   + bias[65+m0]   + bias[97+m0]);
        o0.z = 0.25f * (r2 + bias[m0+2] + bias[34+m0]   + bias[66+m0]   + bias[98+m0]);
        o0.w = 0.25f * (r3 + bias[m0+3] + bias[35+m0]   + bias[67+m0]   + bias[99+m0]);
        o1.x = 0.25f * (r4 + bias[m0+4] + bias[36+m0]   + bias[68+m0]   + bias[100+m0]);
        o1.y = 0.25f * (r5 + bias[m0+5] + bias[37+m0]   + bias[69+m0]   + bias[101+m0]);
        o1.z = 0.25f * (r6 + bias[m0+6] + bias[38+m0]   + bias[70+m0]   + bias[102+m0]);
        o1.w = 0.25f * (r7 + bias[m0+7] + bias[39+m0]   + bias[71+m0]   + bias[103+m0]);
        float* op = out + (size_t)node * 32 + m0;
        *(float4*)op       = o0;
        *(float4*)(op + 4) = o1;
    }
}

// ---------------- launch --------------------------------------------------
extern "C" void kernel_launch(void* const* d_in, const int* in_sizes, int n_in,
                              void* d_out, int out_size, void* d_ws, size_t ws_size,
                              hipStream_t stream)
{
    const float* x      = (const float*)d_in[0];
    const int*   esrc   = (const int*)  d_in[1];
    const int*   edst   = (const int*)  d_in[2];
    const float* fc_w   = (const float*)d_in[3];
    const float* attn_l = (const float*)d_in[4];
    const float* attn_r = (const float*)d_in[5];
    const float* bias   = (const float*)d_in[6];
    float* out = (float*)d_out;

    const int N = in_sizes[0] / IN_DIM;   // 100000
    const int E = in_sizes[1];            // 1600000
    const int NB = (N + NPB - 1) / NPB;   // 391

    size_t o = 0;
    char* base = (char*)d_ws;
    auto alloc = [&](size_t bytes) -> void* {
        void* p = base + o;
        o += (bytes + 255) & ~(size_t)255;
        return p;
    };
    ushort_t* feat16   = (ushort_t*)alloc((size_t)N * 128 * sizeof(ushort_t));
    float* el          = (float*)alloc((size_t)N * 4 * sizeof(float));
    float* er          = (float*)alloc((size_t)N * 4 * sizeof(float));
    int*   row_start   = (int*)  alloc(((size_t)N + 1) * sizeof(int));
    int*   csr         = (int*)  alloc((size_t)E * sizeof(int));
    uint*  binned      = (uint*) alloc((size_t)E * sizeof(uint));
    int*   bucketCount = (int*)  alloc(NB_MAX * sizeof(int));
    int*   bucketStart = (int*)  alloc((NB_MAX + 1) * sizeof(int));
    int*   bucketCursor= (int*)  alloc(NB_MAX * sizeof(int));
    ushort_t* wt       = (ushort_t*)alloc((size_t)128 * 128 * sizeof(ushort_t));
    ushort_t* wt2      = (ushort_t*)alloc((size_t)16 * 128 * sizeof(ushort_t));
    (void)ws_size;

    const int nblkE = (E + EPB - 1) / EPB;    // 196
    const int nblkP = (N + 127) / 128;        // 782 (proj blocks now 128 rows)
    const int projA = nblkP / 2;              // 391 in k3
    const int projB = nblkP - projA;          // 391 in k4

    hipMemsetAsync(bucketCount, 0, NB_MAX * sizeof(int), stream);

    prep_hist_kernel<<<64 + nblkE, 256, 0, stream>>>(
        fc_w, attn_l, attn_r, wt, wt2, edst, bucketCount, E, NB);
    bucket_scan_kernel<<<1, 512, 0, stream>>>(bucketCount, bucketStart,
                                              bucketCursor, row_start, NB, N);
    bin_proj_kernel<<<nblkE + projA, 256, 0, stream>>>(
        esrc, edst, bucketCursor, binned, E, NB, nblkE,
        x, wt, wt2, feat16, el, er, N);
    fine_proj_kernel<<<NB + projB, 256, 0, stream>>>(
        binned, bucketStart, row_start, csr, N, NB, projA,
        x, wt, wt2, feat16, el, er);
    aggregate_kernel<<<(N + 3) / 4, 256, 0, stream>>>((const u32x4*)feat16, el, er,
                                                      row_start, csr, bias, out, N);
}